// Round 2
// 973.126 us; speedup vs baseline: 1.2382x; 1.2382x over previous
//
#include <hip/hip_runtime.h>
#include <stdint.h>

#define NEDGE 500000
#define NUSR  100000
#define NENT  200000

typedef __attribute__((ext_vector_type(8))) short bf16x8;
typedef __attribute__((ext_vector_type(4))) float f32x4;

// ---------------------------------------------------------------------------
// CSR build: histogram -> single-block scan -> cursor scatter.
// ---------------------------------------------------------------------------
__global__ __launch_bounds__(256) void k_hist(
    const int* __restrict__ ui, const int* __restrict__ ii,
    int* __restrict__ deg_u, int* __restrict__ deg_i)
{
  int e = blockIdx.x*256 + threadIdx.x;
  if (e >= NEDGE) return;
  atomicAdd(&deg_u[ui[e]], 1);
  atomicAdd(&deg_i[ii[e]], 1);
}

__device__ void scan_arr(const int* __restrict__ deg, int* __restrict__ off,
                         int n, int* wsum)
{
  const int t = threadIdx.x, lane = t & 63, wv = t >> 6;
  int carry = 0;
  for (int base = 0; base < n; base += 8192){
    int loc[8]; int tsum = 0;
    int i0 = base + t*8;
    #pragma unroll
    for (int j = 0; j < 8; j++){
      int i = i0 + j; int v = (i < n) ? deg[i] : 0;
      loc[j] = tsum; tsum += v;
    }
    int x = tsum;                         // inclusive wave scan
    #pragma unroll
    for (int d = 1; d < 64; d <<= 1){
      int y = __shfl_up(x, d);
      if (lane >= d) x += y;
    }
    if (lane == 63) wsum[wv] = x;
    __syncthreads();
    int wpre = 0, tot = 0;
    #pragma unroll
    for (int w2 = 0; w2 < 16; w2++){
      int s = wsum[w2];
      if (w2 < wv) wpre += s;
      tot += s;
    }
    int tbase = carry + wpre + (x - tsum);  // exclusive thread base
    #pragma unroll
    for (int j = 0; j < 8; j++){
      int i = i0 + j;
      if (i < n) off[i] = tbase + loc[j];
    }
    carry += tot;
    __syncthreads();
  }
  if (t == 0) off[n] = carry;
}

__global__ __launch_bounds__(1024) void k_scan(
    const int* __restrict__ deg_u, int* __restrict__ off_u,
    const int* __restrict__ deg_i, int* __restrict__ off_i)
{
  __shared__ int wsum[16];
  scan_arr(deg_u, off_u, NUSR, wsum);
  __syncthreads();
  scan_arr(deg_i, off_i, NENT, wsum);
}

__global__ __launch_bounds__(256) void k_scatter(
    const int* __restrict__ ui, const int* __restrict__ ii,
    const int* __restrict__ off_u, const int* __restrict__ off_i,
    int* __restrict__ cur_u, int* __restrict__ cur_i,
    int* __restrict__ edge_u, int* __restrict__ edge_i)
{
  int e = blockIdx.x*256 + threadIdx.x;
  if (e >= NEDGE) return;
  int u = ui[e]; int p = atomicAdd(&cur_u[u], 1); edge_u[off_u[u] + p] = e;
  int i = ii[e]; int q = atomicAdd(&cur_i[i], 1); edge_i[off_i[i] + q] = e;
}

// ---------------------------------------------------------------------------
// Per-edge 128->64 matvec via MFMA with 3-way bf16 truncation split.
// x = x0+x1+x2 (bf16 chunks tiling the f32 mantissa -> split is exact);
// D = A0B0 + (A0B1+A1B0) + (A0B2+A1B1+A2B0): dropped terms ~2^-24 relative,
// i.e. the same order as f32 FMA rounding -> argmax flips at baseline rate.
// Block: 512 threads = 8 waves, 128 edges (16/wave). A gathered global->VGPR
// (lane&15 = edge, lane>>4 = k-chunk). W staged once as 3 swizzled bf16
// planes in LDS; transpose buffer ALIASES the W planes (safe after the
// post-K-loop __syncthreads). No barriers inside the K-loop.
// ---------------------------------------------------------------------------
__device__ __forceinline__ void split3(const float4 x0, const float4 x1,
                                       bf16x8* hi, bf16x8* mid, bf16x8* lo)
{
  float xs[8] = {x0.x,x0.y,x0.z,x0.w, x1.x,x1.y,x1.z,x1.w};
  union { unsigned u[4]; bf16x8 v; } H, M, L;
  #pragma unroll
  for (int p = 0; p < 4; p++){
    float a = xs[2*p], b = xs[2*p+1];
    unsigned ua = __float_as_uint(a), ub = __float_as_uint(b);
    H.u[p] = (ua >> 16) | (ub & 0xffff0000u);
    float ra = a - __uint_as_float(ua & 0xffff0000u);
    float rb = b - __uint_as_float(ub & 0xffff0000u);
    unsigned va = __float_as_uint(ra), vb = __float_as_uint(rb);
    M.u[p] = (va >> 16) | (vb & 0xffff0000u);
    float sa = ra - __uint_as_float(va & 0xffff0000u);
    float sb = rb - __uint_as_float(vb & 0xffff0000u);
    L.u[p] = (__float_as_uint(sa) >> 16) | (__float_as_uint(sb) & 0xffff0000u);
  }
  *hi = H.v; *mid = M.v; *lo = L.v;
}

template<int WITH_ARGMAX>
__global__ __launch_bounds__(512,4) void k_matvec(
    const float* __restrict__ rowsA, const float* __restrict__ rowsB,
    const int* __restrict__ idxA, const int* __restrict__ idxB,
    const float* __restrict__ lat,
    const float* __restrict__ Ww, const float* __restrict__ Wb,
    float* __restrict__ rel, int* __restrict__ rtype)
{
  // W planes: hi @0, mid @16384, lo @32768 (each 64 rows x 256B, swizzled).
  // After the post-K-loop barrier this region is reused as the per-wave
  // transpose buffer (8 waves x 16 x 68 f32 = 34816B <= 49152B).
  __shared__ __align__(16) char smem[49152];
  __shared__ float lat_lds[192];
  unsigned short* wlds = (unsigned short*)smem;

  const int t  = threadIdx.x;
  const int e0 = blockIdx.x * 128;

  // ---- stage W (f32 [64][128]) as 3 swizzled bf16 planes: byte ^= (row&7)<<4
  {
    const int n  = t >> 3;              // W row (out dim)
    const int kb = (t & 7) * 16;        // f32 elem base within row
    const float4* s4 = (const float4*)(Ww + n*128 + kb);
    float4 q0 = s4[0], q1 = s4[1], q2 = s4[2], q3 = s4[3];
    float xs[16] = {q0.x,q0.y,q0.z,q0.w, q1.x,q1.y,q1.z,q1.w,
                    q2.x,q2.y,q2.z,q2.w, q3.x,q3.y,q3.z,q3.w};
    unsigned uh[8], um[8], ul[8];
    #pragma unroll
    for (int p = 0; p < 8; p++){
      float a = xs[2*p], b = xs[2*p+1];
      unsigned ua = __float_as_uint(a), ub = __float_as_uint(b);
      uh[p] = (ua >> 16) | (ub & 0xffff0000u);
      float ra = a - __uint_as_float(ua & 0xffff0000u);
      float rb = b - __uint_as_float(ub & 0xffff0000u);
      unsigned va = __float_as_uint(ra), vb = __float_as_uint(rb);
      um[p] = (va >> 16) | (vb & 0xffff0000u);
      float sa = ra - __uint_as_float(va & 0xffff0000u);
      float sb = rb - __uint_as_float(vb & 0xffff0000u);
      ul[p] = (__float_as_uint(sa) >> 16) | (__float_as_uint(sb) & 0xffff0000u);
    }
    char* dh = smem + n*256;
    const unsigned sw = (unsigned)((n & 7) << 4);
    const unsigned b0 = ((unsigned)(kb*2))      ^ sw;
    const unsigned b1 = ((unsigned)(kb*2 + 16)) ^ sw;
    *(uint4*)(dh + b0)         = make_uint4(uh[0],uh[1],uh[2],uh[3]);
    *(uint4*)(dh + b1)         = make_uint4(uh[4],uh[5],uh[6],uh[7]);
    *(uint4*)(dh + 16384 + b0) = make_uint4(um[0],um[1],um[2],um[3]);
    *(uint4*)(dh + 16384 + b1) = make_uint4(um[4],um[5],um[6],um[7]);
    *(uint4*)(dh + 32768 + b0) = make_uint4(ul[0],ul[1],ul[2],ul[3]);
    *(uint4*)(dh + 32768 + b1) = make_uint4(ul[4],ul[5],ul[6],ul[7]);
  }
  if (WITH_ARGMAX && t < 192) lat_lds[t] = lat[t];
  __syncthreads();

  const int w = t >> 6, l = t & 63;
  const int g = l >> 4, c = l & 15;

  const int e_lane = min(e0 + w*16 + c, NEDGE-1);
  const int ia = idxA[e_lane], ib = idxB[e_lane];
  const float* pa = rowsA + (size_t)ia*64 + g*8;
  const float* pb = rowsB + (size_t)ib*64 + g*8;

  f32x4 acc[4];
  #pragma unroll
  for (int nt = 0; nt < 4; nt++){
    float bv = Wb[nt*16 + c];           // bias folded into C-init
    f32x4 a = {bv, bv, bv, bv};
    acc[nt] = a;
  }

  const unsigned sw = (unsigned)((c & 7) << 4);
  #pragma unroll
  for (int kk = 0; kk < 4; kk++){       // K=128 in 4 MFMA steps of 32
    const float* src = (kk < 2) ? (pa + (kk & 1)*32) : (pb + (kk & 1)*32);
    float4 x0 = *(const float4*)src;
    float4 x1 = *(const float4*)(src + 4);
    bf16x8 a0, a1, a2;
    split3(x0, x1, &a0, &a1, &a2);
    const unsigned xoff = ((unsigned)(kk*64 + g*16)) ^ sw;
    #pragma unroll
    for (int nt = 0; nt < 4; nt++){
      const char* base = smem + (unsigned)((nt*16 + c)*256) + xoff;
      bf16x8 b0 = *(const bf16x8*)base;
      bf16x8 b1 = *(const bf16x8*)(base + 16384);
      bf16x8 b2 = *(const bf16x8*)(base + 32768);
      // smallest-magnitude terms first for accumulation
      acc[nt] = __builtin_amdgcn_mfma_f32_16x16x32_bf16(a0, b2, acc[nt], 0, 0, 0);
      acc[nt] = __builtin_amdgcn_mfma_f32_16x16x32_bf16(a1, b1, acc[nt], 0, 0, 0);
      acc[nt] = __builtin_amdgcn_mfma_f32_16x16x32_bf16(a2, b0, acc[nt], 0, 0, 0);
      acc[nt] = __builtin_amdgcn_mfma_f32_16x16x32_bf16(a0, b1, acc[nt], 0, 0, 0);
      acc[nt] = __builtin_amdgcn_mfma_f32_16x16x32_bf16(a1, b0, acc[nt], 0, 0, 0);
      acc[nt] = __builtin_amdgcn_mfma_f32_16x16x32_bf16(a0, b0, acc[nt], 0, 0, 0);
    }
  }

  // leaky_relu(0.01)
  #pragma unroll
  for (int nt = 0; nt < 4; nt++)
    #pragma unroll
    for (int r = 0; r < 4; r++){
      float v = acc[nt][r];
      acc[nt][r] = v > 0.f ? v : 0.01f*v;
    }

  // argmax over latent scores, straight from f32 accumulators
  if (WITH_ARGMAX){
    int rt[4];
    #pragma unroll
    for (int r = 0; r < 4; r++){
      float s0 = 0.f, s1 = 0.f, s2 = 0.f;
      #pragma unroll
      for (int nt = 0; nt < 4; nt++){
        float a = acc[nt][r];
        s0 += a * lat_lds[      nt*16 + c];
        s1 += a * lat_lds[ 64 + nt*16 + c];
        s2 += a * lat_lds[128 + nt*16 + c];
      }
      #pragma unroll
      for (int m = 1; m < 16; m <<= 1){   // reduce across out-dims (lane&15)
        s0 += __shfl_xor(s0, m);
        s1 += __shfl_xor(s1, m);
        s2 += __shfl_xor(s2, m);
      }
      int bf = 0; float bs = s0;
      if (s1 > bs){ bs = s1; bf = 1; }   // strict > : first-max like jnp.argmax
      if (s2 > bs){ bs = s2; bf = 2; }
      rt[r] = bf;
    }
    if (c == 0){
      int eb = e0 + w*16 + g*4;
      if (eb < NEDGE)
        *(int4*)(rtype + eb) = make_int4(rt[0], rt[1], rt[2], rt[3]);
    }
  }

  // All waves have finished reading the W planes after this barrier;
  // smem is then reused as the per-wave transpose buffer.
  __syncthreads();
  float* tb = (float*)smem + w*1088;    // [16][68] f32, 16B-aligned rows
  #pragma unroll
  for (int nt = 0; nt < 4; nt++)
    #pragma unroll
    for (int r = 0; r < 4; r++)
      tb[(g*4 + r)*68 + nt*16 + c] = acc[nt][r];

  #pragma unroll
  for (int r = 0; r < 4; r++){
    int g2 = l + 64*r;
    int el = g2 >> 4, c4 = (g2 & 15) << 2;
    int er = e0 + w*16 + el;
    if (er < NEDGE)
      *(float4*)(rel + (size_t)er*64 + c4) = *(const float4*)&tb[el*68 + c4];
  }
}

// ---------------------------------------------------------------------------
// User side, one wave per user: both reduction levels + squash + softmax mix.
// ---------------------------------------------------------------------------
__global__ __launch_bounds__(256) void k_user(
    const float* __restrict__ ent, const float* __restrict__ usr,
    const float* __restrict__ w3,
    const int* __restrict__ iidx, const int* __restrict__ rtype,
    const float* __restrict__ rel,
    const int* __restrict__ off_u, const int* __restrict__ edge_u,
    float* __restrict__ out_user)
{
  const int lane = threadIdx.x & 63;
  const int u = blockIdx.x*4 + (threadIdx.x >> 6);
  if (u >= NUSR) return;
  const int beg = off_u[u], end = off_u[u+1];

  float s0=0.f, s1=0.f, s2=0.f; int c0=0, c1=0, c2=0;
  for (int k = beg; k < end; k++){
    int e = edge_u[k];
    int f = rtype[e];
    float ip = ent[(size_t)iidx[e]*64 + lane];
    if (f == 0){ s0 += ip; c0++; }
    else if (f == 1){ s1 += ip; c1++; }
    else { s2 += ip; c2++; }
  }
  const float d0 = fmaxf((float)c0, 1.f);
  const float d1 = fmaxf((float)c1, 1.f);
  const float d2 = fmaxf((float)c2, 1.f);

  float a0=0.f, a1=0.f, a2=0.f;
  for (int k = beg; k < end; k++){
    int e = edge_u[k];
    int f = rtype[e];
    float ip = ent[(size_t)iidx[e]*64 + lane];
    float rv = rel[(size_t)e*64 + lane];
    float ss = (f == 0) ? s0 : ((f == 1) ? s1 : s2);
    float dd = (f == 0) ? d0 : ((f == 1) ? d1 : d2);
    float p = rv * ss;
    #pragma unroll
    for (int m = 1; m < 64; m <<= 1) p += __shfl_xor(p, m);
    float sim = p / dd;
    if (f == 0) a0 += sim*ip; else if (f == 1) a1 += sim*ip; else a2 += sim*ip;
  }

  float wa = w3[0], wb = w3[1], wc = w3[2];
  float mx = fmaxf(wa, fmaxf(wb, wc));
  float ea = expf(wa-mx), eb = expf(wb-mx), ec = expf(wc-mx);
  float inv = 1.f/(ea+eb+ec);
  float ue = usr[(size_t)u*64 + lane];
  float av[3] = {a0,a1,a2}, dv[3] = {d0,d1,d2}, wv[3] = {ea*inv, eb*inv, ec*inv};
  float o = 0.f;
  #pragma unroll
  for (int f = 0; f < 3; f++){
    float v = av[f]/dv[f];
    float n2 = v*v;
    #pragma unroll
    for (int m = 1; m < 64; m <<= 1) n2 += __shfl_xor(n2, m);
    float n = sqrtf(n2);
    float fac = (n2/(n2 + 1.f)) / fmaxf(n, 1e-12f);
    o += wv[f]*(fac*v + ue);
  }
  out_user[(size_t)u*64 + lane] = o;
}

// ---------------------------------------------------------------------------
// Entity side, one wave per entity.
// ---------------------------------------------------------------------------
__global__ __launch_bounds__(256) void k_ent(
    const float* __restrict__ ent, const float* __restrict__ usr,
    const int* __restrict__ uidx, const float* __restrict__ rel,
    const int* __restrict__ off_i, const int* __restrict__ edge_i,
    float* __restrict__ out_ent)
{
  const int lane = threadIdx.x & 63;
  const int i = blockIdx.x*4 + (threadIdx.x >> 6);
  if (i >= NENT) return;
  const int beg = off_i[i], end = off_i[i+1];

  float s = 0.f;
  for (int k = beg; k < end; k++){
    int e = edge_i[k];
    s += usr[(size_t)uidx[e]*64 + lane];
  }
  const float d = fmaxf((float)(end - beg), 1.f);

  float a = 0.f;
  for (int k = beg; k < end; k++){
    int e = edge_i[k];
    float up = usr[(size_t)uidx[e]*64 + lane];
    float rv = rel[(size_t)e*64 + lane];
    float p = rv * s;
    #pragma unroll
    for (int m = 1; m < 64; m <<= 1) p += __shfl_xor(p, m);
    a += (p/d)*up;
  }
  float v = a/d;
  float n2 = v*v;
  #pragma unroll
  for (int m = 1; m < 64; m <<= 1) n2 += __shfl_xor(n2, m);
  float n = sqrtf(n2);
  float fac = (n2/(n2 + 1.f)) / fmaxf(n, 1e-12f);
  out_ent[(size_t)i*64 + lane] = fac*v + ent[(size_t)i*64 + lane];
}

// ---------------------------------------------------------------------------
// Workspace layout (float/int element offsets). Total: 265.6 MB (unchanged).
//   rel_ui f32 [E*64]      @ 0            (128 MB)
//   rel_iu f32 [E*64]      @ 32,000,000   (128 MB)
//   rtype      [E]         @ 64,000,000
//   zero-block             @ 64,500,000:  deg_u(100k) cur_u(100k) deg_i(200k) cur_i(200k)
//   off_u      [U+1]       @ 65,100,000
//   off_i      [ENT+1]     @ 65,200,004
//   edge_u     [E]         @ 65,400,008
//   edge_i     [E]         @ 65,900,008
// ---------------------------------------------------------------------------
extern "C" void kernel_launch(void* const* d_in, const int* in_sizes, int n_in,
                              void* d_out, int out_size, void* d_ws, size_t ws_size,
                              hipStream_t stream) {
  const float* ent = (const float*)d_in[0];
  const float* usr = (const float*)d_in[1];
  const float* lat = (const float*)d_in[2];
  const int*   ui  = (const int*)d_in[3];
  const int*   ii  = (const int*)d_in[4];
  const float* Ww  = (const float*)d_in[5];
  const float* Wb  = (const float*)d_in[6];
  const float* Wiw = (const float*)d_in[7];
  const float* Wib = (const float*)d_in[8];
  const float* w3  = (const float*)d_in[9];

  float* ws = (float*)d_ws;
  float* rel_ui = ws;
  float* rel_iu = ws + 32000000ull;
  int*   rtype  = (int*)(ws + 64000000ull);
  int*   deg_u  = (int*)(ws + 64500000ull);
  int*   cur_u  = deg_u + 100000;
  int*   deg_i  = cur_u + 100000;
  int*   cur_i  = deg_i + 200000;
  int*   off_u  = (int*)(ws + 65100000ull);
  int*   off_i  = (int*)(ws + 65200004ull);
  int*   edge_u = (int*)(ws + 65400008ull);
  int*   edge_i = (int*)(ws + 65900008ull);

  float* out_ent  = (float*)d_out;
  float* out_user = (float*)d_out + (size_t)NENT*64;

  hipMemsetAsync(deg_u, 0, 600000*sizeof(int), stream);   // deg+cur, both sides

  k_hist<<<1954, 256, 0, stream>>>(ui, ii, deg_u, deg_i);
  k_scan<<<1, 1024, 0, stream>>>(deg_u, off_u, deg_i, off_i);
  k_scatter<<<1954, 256, 0, stream>>>(ui, ii, off_u, off_i,
                                      cur_u, cur_i, edge_u, edge_i);

  // relation_ui = leaky(concat([user, item]) @ Ww^T + b), + argmax -> rtype
  k_matvec<1><<<3907, 512, 0, stream>>>(usr, ent, ui, ii, lat, Ww, Wb,
                                        rel_ui, rtype);
  // relation_iu = leaky(concat([item, user]) @ Wiw^T + b)
  k_matvec<0><<<3907, 512, 0, stream>>>(ent, usr, ii, ui, lat, Wiw, Wib,
                                        rel_iu, rtype);

  k_user<<<25000, 256, 0, stream>>>(ent, usr, w3, ii, rtype, rel_ui,
                                    off_u, edge_u, out_user);
  k_ent<<<50000, 256, 0, stream>>>(ent, usr, ui, rel_iu,
                                   off_i, edge_i, out_ent);
}

// Round 3
// 726.482 us; speedup vs baseline: 1.6586x; 1.3395x over previous
//
#include <hip/hip_runtime.h>
#include <stdint.h>

#define NEDGE 500000
#define NUSR  100000
#define NENT  200000

typedef __attribute__((ext_vector_type(8))) short bf16x8;
typedef __attribute__((ext_vector_type(4))) float f32x4;

// ---------------------------------------------------------------------------
// CSR build: histogram -> single-block scan -> cursor scatter.
// k_scatter now writes pair[k] = (user,item) per CSR slot for BOTH sides;
// all downstream kernels (matvec, user, ent) work in CSR-slot order, so
// rel/rtype are produced contiguous and the aggregation loops stream them.
// ---------------------------------------------------------------------------
__global__ __launch_bounds__(256) void k_hist(
    const int* __restrict__ ui, const int* __restrict__ ii,
    int* __restrict__ deg_u, int* __restrict__ deg_i)
{
  int e = blockIdx.x*256 + threadIdx.x;
  if (e >= NEDGE) return;
  atomicAdd(&deg_u[ui[e]], 1);
  atomicAdd(&deg_i[ii[e]], 1);
}

__device__ void scan_arr(const int* __restrict__ deg, int* __restrict__ off,
                         int n, int* wsum)
{
  const int t = threadIdx.x, lane = t & 63, wv = t >> 6;
  int carry = 0;
  for (int base = 0; base < n; base += 8192){
    int loc[8]; int tsum = 0;
    int i0 = base + t*8;
    #pragma unroll
    for (int j = 0; j < 8; j++){
      int i = i0 + j; int v = (i < n) ? deg[i] : 0;
      loc[j] = tsum; tsum += v;
    }
    int x = tsum;                         // inclusive wave scan
    #pragma unroll
    for (int d = 1; d < 64; d <<= 1){
      int y = __shfl_up(x, d);
      if (lane >= d) x += y;
    }
    if (lane == 63) wsum[wv] = x;
    __syncthreads();
    int wpre = 0, tot = 0;
    #pragma unroll
    for (int w2 = 0; w2 < 16; w2++){
      int s = wsum[w2];
      if (w2 < wv) wpre += s;
      tot += s;
    }
    int tbase = carry + wpre + (x - tsum);  // exclusive thread base
    #pragma unroll
    for (int j = 0; j < 8; j++){
      int i = i0 + j;
      if (i < n) off[i] = tbase + loc[j];
    }
    carry += tot;
    __syncthreads();
  }
  if (t == 0) off[n] = carry;
}

__global__ __launch_bounds__(1024) void k_scan(
    const int* __restrict__ deg_u, int* __restrict__ off_u,
    const int* __restrict__ deg_i, int* __restrict__ off_i)
{
  __shared__ int wsum[16];
  scan_arr(deg_u, off_u, NUSR, wsum);
  __syncthreads();
  scan_arr(deg_i, off_i, NENT, wsum);
}

__global__ __launch_bounds__(256) void k_scatter(
    const int* __restrict__ ui, const int* __restrict__ ii,
    const int* __restrict__ off_u, const int* __restrict__ off_i,
    int* __restrict__ cur_u, int* __restrict__ cur_i,
    int2* __restrict__ pair_u, int2* __restrict__ pair_i)
{
  int e = blockIdx.x*256 + threadIdx.x;
  if (e >= NEDGE) return;
  int u = ui[e], it = ii[e];
  int p = atomicAdd(&cur_u[u],  1); pair_u[off_u[u]  + p] = make_int2(u, it);
  int q = atomicAdd(&cur_i[it], 1); pair_i[off_i[it] + q] = make_int2(u, it);
}

// ---------------------------------------------------------------------------
// Per-slot 128->64 matvec via MFMA with 3-way bf16 truncation split (exact
// mantissa tiling; dropped terms ~2^-24 rel, same order as f32 rounding).
// Processes CSR SLOTS: row indices come from pair[slot], outputs rel[slot]
// and rtype[slot] contiguous. SWAP picks which pair field feeds A (concat
// order: ui-direction A=user=.x; iu-direction A=item=.y).
// Block: 512 threads = 8 waves, 128 slots (16/wave).
// ---------------------------------------------------------------------------
template<int WITH_ARGMAX, int SWAP>
__global__ __launch_bounds__(512,4) void k_matvec(
    const float* __restrict__ rowsA, const float* __restrict__ rowsB,
    const int2* __restrict__ pair,
    const float* __restrict__ lat,
    const float* __restrict__ Ww, const float* __restrict__ Wb,
    float* __restrict__ rel, int* __restrict__ rtype)
{
  // W planes: hi @0, mid @16384, lo @32768 (each 64 rows x 256B, swizzled).
  // After the post-K-loop barrier this region is reused as the per-wave
  // transpose buffer (8 waves x 16 x 68 f32 = 34816B <= 49152B).
  __shared__ __align__(16) char smem[49152];
  __shared__ float lat_lds[192];

  const int t  = threadIdx.x;
  const int e0 = blockIdx.x * 128;

  // ---- stage W (f32 [64][128]) as 3 swizzled bf16 planes: byte ^= (row&7)<<4
  {
    const int n  = t >> 3;              // W row (out dim)
    const int kb = (t & 7) * 16;        // f32 elem base within row
    const float4* s4 = (const float4*)(Ww + n*128 + kb);
    float4 q0 = s4[0], q1 = s4[1], q2 = s4[2], q3 = s4[3];
    float xs[16] = {q0.x,q0.y,q0.z,q0.w, q1.x,q1.y,q1.z,q1.w,
                    q2.x,q2.y,q2.z,q2.w, q3.x,q3.y,q3.z,q3.w};
    unsigned uh[8], um[8], ul[8];
    #pragma unroll
    for (int p = 0; p < 8; p++){
      float a = xs[2*p], b = xs[2*p+1];
      unsigned ua = __float_as_uint(a), ub = __float_as_uint(b);
      uh[p] = (ua >> 16) | (ub & 0xffff0000u);
      float ra = a - __uint_as_float(ua & 0xffff0000u);
      float rb = b - __uint_as_float(ub & 0xffff0000u);
      unsigned va = __float_as_uint(ra), vb = __float_as_uint(rb);
      um[p] = (va >> 16) | (vb & 0xffff0000u);
      float sa = ra - __uint_as_float(va & 0xffff0000u);
      float sb = rb - __uint_as_float(vb & 0xffff0000u);
      ul[p] = (__float_as_uint(sa) >> 16) | (__float_as_uint(sb) & 0xffff0000u);
    }
    char* dh = smem + n*256;
    const unsigned sw = (unsigned)((n & 7) << 4);
    const unsigned b0 = ((unsigned)(kb*2))      ^ sw;
    const unsigned b1 = ((unsigned)(kb*2 + 16)) ^ sw;
    *(uint4*)(dh + b0)         = make_uint4(uh[0],uh[1],uh[2],uh[3]);
    *(uint4*)(dh + b1)         = make_uint4(uh[4],uh[5],uh[6],uh[7]);
    *(uint4*)(dh + 16384 + b0) = make_uint4(um[0],um[1],um[2],um[3]);
    *(uint4*)(dh + 16384 + b1) = make_uint4(um[4],um[5],um[6],um[7]);
    *(uint4*)(dh + 32768 + b0) = make_uint4(ul[0],ul[1],ul[2],ul[3]);
    *(uint4*)(dh + 32768 + b1) = make_uint4(ul[4],ul[5],ul[6],ul[7]);
  }
  if (WITH_ARGMAX && t < 192) lat_lds[t] = lat[t];
  __syncthreads();

  const int w = t >> 6, l = t & 63;
  const int g = l >> 4, c = l & 15;

  const int sl = min(e0 + w*16 + c, NEDGE-1);
  const int2 pr = pair[sl];
  const int ia = SWAP ? pr.y : pr.x;
  const int ib = SWAP ? pr.x : pr.y;
  const float* pa = rowsA + (size_t)ia*64 + g*8;
  const float* pb = rowsB + (size_t)ib*64 + g*8;

  f32x4 acc[4];
  #pragma unroll
  for (int nt = 0; nt < 4; nt++){
    float bv = Wb[nt*16 + c];           // bias folded into C-init
    f32x4 a = {bv, bv, bv, bv};
    acc[nt] = a;
  }

  const unsigned sw = (unsigned)((c & 7) << 4);
  #pragma unroll
  for (int kk = 0; kk < 4; kk++){       // K=128 in 4 MFMA steps of 32
    const float* src = (kk < 2) ? (pa + (kk & 1)*32) : (pb + (kk & 1)*32);
    float4 x0 = *(const float4*)src;
    float4 x1 = *(const float4*)(src + 4);
    // 3-way truncation split
    float xsv[8] = {x0.x,x0.y,x0.z,x0.w, x1.x,x1.y,x1.z,x1.w};
    union { unsigned u[4]; bf16x8 v; } H, M, L;
    #pragma unroll
    for (int p = 0; p < 4; p++){
      float a = xsv[2*p], b = xsv[2*p+1];
      unsigned ua = __float_as_uint(a), ub = __float_as_uint(b);
      H.u[p] = (ua >> 16) | (ub & 0xffff0000u);
      float ra = a - __uint_as_float(ua & 0xffff0000u);
      float rb = b - __uint_as_float(ub & 0xffff0000u);
      unsigned va = __float_as_uint(ra), vb = __float_as_uint(rb);
      M.u[p] = (va >> 16) | (vb & 0xffff0000u);
      float sa = ra - __uint_as_float(va & 0xffff0000u);
      float sb = rb - __uint_as_float(vb & 0xffff0000u);
      L.u[p] = (__float_as_uint(sa) >> 16) | (__float_as_uint(sb) & 0xffff0000u);
    }
    bf16x8 a0 = H.v, a1 = M.v, a2 = L.v;
    const unsigned xoff = ((unsigned)(kk*64 + g*16)) ^ sw;
    #pragma unroll
    for (int nt = 0; nt < 4; nt++){
      const char* base = smem + (unsigned)((nt*16 + c)*256) + xoff;
      bf16x8 b0 = *(const bf16x8*)base;
      bf16x8 b1 = *(const bf16x8*)(base + 16384);
      bf16x8 b2 = *(const bf16x8*)(base + 32768);
      // smallest-magnitude terms first for accumulation
      acc[nt] = __builtin_amdgcn_mfma_f32_16x16x32_bf16(a0, b2, acc[nt], 0, 0, 0);
      acc[nt] = __builtin_amdgcn_mfma_f32_16x16x32_bf16(a1, b1, acc[nt], 0, 0, 0);
      acc[nt] = __builtin_amdgcn_mfma_f32_16x16x32_bf16(a2, b0, acc[nt], 0, 0, 0);
      acc[nt] = __builtin_amdgcn_mfma_f32_16x16x32_bf16(a0, b1, acc[nt], 0, 0, 0);
      acc[nt] = __builtin_amdgcn_mfma_f32_16x16x32_bf16(a1, b0, acc[nt], 0, 0, 0);
      acc[nt] = __builtin_amdgcn_mfma_f32_16x16x32_bf16(a0, b0, acc[nt], 0, 0, 0);
    }
  }

  // leaky_relu(0.01)
  #pragma unroll
  for (int nt = 0; nt < 4; nt++)
    #pragma unroll
    for (int r = 0; r < 4; r++){
      float v = acc[nt][r];
      acc[nt][r] = v > 0.f ? v : 0.01f*v;
    }

  // argmax over latent scores, straight from f32 accumulators
  if (WITH_ARGMAX){
    int rt[4];
    #pragma unroll
    for (int r = 0; r < 4; r++){
      float s0 = 0.f, s1 = 0.f, s2 = 0.f;
      #pragma unroll
      for (int nt = 0; nt < 4; nt++){
        float a = acc[nt][r];
        s0 += a * lat_lds[      nt*16 + c];
        s1 += a * lat_lds[ 64 + nt*16 + c];
        s2 += a * lat_lds[128 + nt*16 + c];
      }
      #pragma unroll
      for (int m = 1; m < 16; m <<= 1){   // reduce across out-dims (lane&15)
        s0 += __shfl_xor(s0, m);
        s1 += __shfl_xor(s1, m);
        s2 += __shfl_xor(s2, m);
      }
      int bf = 0; float bs = s0;
      if (s1 > bs){ bs = s1; bf = 1; }   // strict > : first-max like jnp.argmax
      if (s2 > bs){ bs = s2; bf = 2; }
      rt[r] = bf;
    }
    if (c == 0){
      int eb = e0 + w*16 + g*4;
      if (eb < NEDGE)
        *(int4*)(rtype + eb) = make_int4(rt[0], rt[1], rt[2], rt[3]);
    }
  }

  // All waves have finished reading the W planes after this barrier;
  // smem is then reused as the per-wave transpose buffer.
  __syncthreads();
  float* tb = (float*)smem + w*1088;    // [16][68] f32, 16B-aligned rows
  #pragma unroll
  for (int nt = 0; nt < 4; nt++)
    #pragma unroll
    for (int r = 0; r < 4; r++)
      tb[(g*4 + r)*68 + nt*16 + c] = acc[nt][r];

  #pragma unroll
  for (int r = 0; r < 4; r++){
    int g2 = l + 64*r;
    int el = g2 >> 4, c4 = (g2 & 15) << 2;
    int er = e0 + w*16 + el;
    if (er < NEDGE)
      *(float4*)(rel + (size_t)er*64 + c4) = *(const float4*)&tb[el*68 + c4];
  }
}

// ---------------------------------------------------------------------------
// User side, one wave per user, 4 edge-groups x 16 lanes (f32x4 dim slice).
// All per-slot streams (pair, rtype, rel) are CSR-contiguous; the only
// gather is the depth-1 ent-row read.
// ---------------------------------------------------------------------------
__global__ __launch_bounds__(256) void k_user(
    const float* __restrict__ ent, const float* __restrict__ usr,
    const float* __restrict__ w3,
    const int2* __restrict__ pair_u, const int* __restrict__ rtype,
    const float* __restrict__ rel,
    const int* __restrict__ off_u, float* __restrict__ out_user)
{
  const int l = threadIdx.x & 63;
  const int u = blockIdx.x*4 + (threadIdx.x >> 6);
  if (u >= NUSR) return;
  const int g = l >> 4, c = l & 15;
  const int beg = off_u[u], end = off_u[u+1];

  const f32x4 z = {0.f,0.f,0.f,0.f};
  f32x4 s0 = z, s1 = z, s2 = z;
  int c0 = 0, c1 = 0, c2 = 0;
  for (int k = beg + g; k < end; k += 4){
    int item = pair_u[k].y;
    int f = rtype[k];
    f32x4 ip = *(const f32x4*)(ent + (size_t)item*64 + (c<<2));
    if (f == 0){ s0 += ip; c0++; }
    else if (f == 1){ s1 += ip; c1++; }
    else { s2 += ip; c2++; }
  }
  // cross-group combine (groups hold disjoint edge subsets)
  #pragma unroll
  for (int m = 16; m < 64; m <<= 1){
    #pragma unroll
    for (int j = 0; j < 4; j++){
      s0[j] += __shfl_xor(s0[j], m);
      s1[j] += __shfl_xor(s1[j], m);
      s2[j] += __shfl_xor(s2[j], m);
    }
    c0 += __shfl_xor(c0, m);
    c1 += __shfl_xor(c1, m);
    c2 += __shfl_xor(c2, m);
  }
  const float d0 = fmaxf((float)c0, 1.f);
  const float d1 = fmaxf((float)c1, 1.f);
  const float d2 = fmaxf((float)c2, 1.f);

  f32x4 a0 = z, a1 = z, a2 = z;
  for (int k = beg + g; k < end; k += 4){
    int item = pair_u[k].y;
    int f = rtype[k];
    f32x4 ip = *(const f32x4*)(ent + (size_t)item*64 + (c<<2));
    f32x4 rv = *(const f32x4*)(rel + (size_t)k*64 + (c<<2));
    f32x4 sf = (f == 0) ? s0 : ((f == 1) ? s1 : s2);
    float dd = (f == 0) ? d0 : ((f == 1) ? d1 : d2);
    float p = rv[0]*sf[0] + rv[1]*sf[1] + rv[2]*sf[2] + rv[3]*sf[3];
    #pragma unroll
    for (int m = 1; m < 16; m <<= 1) p += __shfl_xor(p, m);
    float sim = p / dd;                 // dot(rel, u_) with mean folded in
    f32x4 tv = ip * sim;
    if (f == 0) a0 += tv; else if (f == 1) a1 += tv; else a2 += tv;
  }
  #pragma unroll
  for (int m = 16; m < 64; m <<= 1){
    #pragma unroll
    for (int j = 0; j < 4; j++){
      a0[j] += __shfl_xor(a0[j], m);
      a1[j] += __shfl_xor(a1[j], m);
      a2[j] += __shfl_xor(a2[j], m);
    }
  }

  float wa = w3[0], wb = w3[1], wc = w3[2];
  float mx = fmaxf(wa, fmaxf(wb, wc));
  float ea = expf(wa-mx), eb = expf(wb-mx), ec = expf(wc-mx);
  float inv = 1.f/(ea+eb+ec);
  f32x4 ue = *(const f32x4*)(usr + (size_t)u*64 + (c<<2));
  f32x4 av[3] = {a0, a1, a2};
  float dv[3] = {d0, d1, d2}, wv[3] = {ea*inv, eb*inv, ec*inv};
  f32x4 o = z;
  #pragma unroll
  for (int f = 0; f < 3; f++){
    f32x4 v = av[f] / dv[f];
    float n2 = v[0]*v[0] + v[1]*v[1] + v[2]*v[2] + v[3]*v[3];
    #pragma unroll
    for (int m = 1; m < 16; m <<= 1) n2 += __shfl_xor(n2, m);
    float n = sqrtf(n2);
    float fac = (n2/(n2 + 1.f)) / fmaxf(n, 1e-12f);
    o += (v * fac + ue) * wv[f];
  }
  if (g == 0)
    *(f32x4*)(out_user + (size_t)u*64 + (c<<2)) = o;
}

// ---------------------------------------------------------------------------
// Entity side, one wave per entity, same 4x16 layout.
// ---------------------------------------------------------------------------
__global__ __launch_bounds__(256) void k_ent(
    const float* __restrict__ ent, const float* __restrict__ usr,
    const int2* __restrict__ pair_i, const float* __restrict__ rel,
    const int* __restrict__ off_i, float* __restrict__ out_ent)
{
  const int l = threadIdx.x & 63;
  const int i = blockIdx.x*4 + (threadIdx.x >> 6);
  if (i >= NENT) return;
  const int g = l >> 4, c = l & 15;
  const int beg = off_i[i], end = off_i[i+1];

  const f32x4 z = {0.f,0.f,0.f,0.f};
  f32x4 s = z;
  for (int k = beg + g; k < end; k += 4){
    int us = pair_i[k].x;
    s += *(const f32x4*)(usr + (size_t)us*64 + (c<<2));
  }
  #pragma unroll
  for (int m = 16; m < 64; m <<= 1){
    #pragma unroll
    for (int j = 0; j < 4; j++) s[j] += __shfl_xor(s[j], m);
  }
  const float d = fmaxf((float)(end - beg), 1.f);

  f32x4 a = z;
  for (int k = beg + g; k < end; k += 4){
    int us = pair_i[k].x;
    f32x4 up = *(const f32x4*)(usr + (size_t)us*64 + (c<<2));
    f32x4 rv = *(const f32x4*)(rel + (size_t)k*64 + (c<<2));
    float p = rv[0]*s[0] + rv[1]*s[1] + rv[2]*s[2] + rv[3]*s[3];
    #pragma unroll
    for (int m = 1; m < 16; m <<= 1) p += __shfl_xor(p, m);
    a += up * (p / d);
  }
  #pragma unroll
  for (int m = 16; m < 64; m <<= 1){
    #pragma unroll
    for (int j = 0; j < 4; j++) a[j] += __shfl_xor(a[j], m);
  }

  f32x4 v = a / d;
  float n2 = v[0]*v[0] + v[1]*v[1] + v[2]*v[2] + v[3]*v[3];
  #pragma unroll
  for (int m = 1; m < 16; m <<= 1) n2 += __shfl_xor(n2, m);
  float n = sqrtf(n2);
  float fac = (n2/(n2 + 1.f)) / fmaxf(n, 1e-12f);
  f32x4 ev = *(const f32x4*)(ent + (size_t)i*64 + (c<<2));
  if (g == 0)
    *(f32x4*)(out_ent + (size_t)i*64 + (c<<2)) = v * fac + ev;
}

// ---------------------------------------------------------------------------
// Workspace layout (f32 element offsets). Total: 141.6 MB.
// rel_ui and rel_iu SHARE one buffer (disjoint lifetimes given launch order
// matvec<ui> -> k_user -> matvec<iu> -> k_ent); working set now fits L3.
//   rel     f32 [E*64]   @ 0            (128 MB)
//   zero-block           @ 32,000,000:  deg_u(100k) cur_u(100k) deg_i(200k) cur_i(200k)
//   off_u   [U+1]        @ 32,600,000
//   off_i   [ENT+1]      @ 32,700,004
//   pair_u  int2 [E]     @ 32,900,008   (byte offset %8 == 0)
//   pair_i  int2 [E]     @ 33,900,008
//   rtype   [E]          @ 34,900,008
// ---------------------------------------------------------------------------
extern "C" void kernel_launch(void* const* d_in, const int* in_sizes, int n_in,
                              void* d_out, int out_size, void* d_ws, size_t ws_size,
                              hipStream_t stream) {
  const float* ent = (const float*)d_in[0];
  const float* usr = (const float*)d_in[1];
  const float* lat = (const float*)d_in[2];
  const int*   ui  = (const int*)d_in[3];
  const int*   ii  = (const int*)d_in[4];
  const float* Ww  = (const float*)d_in[5];
  const float* Wb  = (const float*)d_in[6];
  const float* Wiw = (const float*)d_in[7];
  const float* Wib = (const float*)d_in[8];
  const float* w3  = (const float*)d_in[9];

  float* ws = (float*)d_ws;
  float* rel    = ws;
  int*   deg_u  = (int*)(ws + 32000000ull);
  int*   cur_u  = deg_u + 100000;
  int*   deg_i  = cur_u + 100000;
  int*   cur_i  = deg_i + 200000;
  int*   off_u  = (int*)(ws + 32600000ull);
  int*   off_i  = (int*)(ws + 32700004ull);
  int2*  pair_u = (int2*)(ws + 32900008ull);
  int2*  pair_i = (int2*)(ws + 33900008ull);
  int*   rtype  = (int*)(ws + 34900008ull);

  float* out_ent  = (float*)d_out;
  float* out_user = (float*)d_out + (size_t)NENT*64;

  hipMemsetAsync(deg_u, 0, 600000*sizeof(int), stream);   // deg+cur, both sides

  k_hist<<<1954, 256, 0, stream>>>(ui, ii, deg_u, deg_i);
  k_scan<<<1, 1024, 0, stream>>>(deg_u, off_u, deg_i, off_i);
  k_scatter<<<1954, 256, 0, stream>>>(ui, ii, off_u, off_i,
                                      cur_u, cur_i, pair_u, pair_i);

  // relation_ui = leaky(concat([user, item]) @ Ww^T + b), + argmax -> rtype
  k_matvec<1,0><<<3907, 512, 0, stream>>>(usr, ent, pair_u, lat, Ww, Wb,
                                          rel, rtype);
  k_user<<<25000, 256, 0, stream>>>(ent, usr, w3, pair_u, rtype, rel,
                                    off_u, out_user);
  // relation_iu = leaky(concat([item, user]) @ Wiw^T + b)  (reuses rel buffer)
  k_matvec<0,1><<<3907, 512, 0, stream>>>(ent, usr, pair_i, lat, Wiw, Wib,
                                          rel, rtype);
  k_ent<<<50000, 256, 0, stream>>>(ent, usr, pair_i, rel,
                                   off_i, out_ent);
}

// Round 4
// 565.774 us; speedup vs baseline: 2.1297x; 1.2841x over previous
//
#include <hip/hip_runtime.h>
#include <stdint.h>

#define NEDGE 500000
#define NUSR  100000
#define NENT  200000

// scan tiling: 8192 elems/block; 13 blocks cover NUSR, 25 cover NENT
#define NBU 13
#define NBI 25
#define NBT 38

typedef __attribute__((ext_vector_type(8))) short bf16x8;
typedef __attribute__((ext_vector_type(4))) float f32x4;

// ---------------------------------------------------------------------------
// CSR build: histogram -> two-pass parallel scan -> cursor scatter.
// k_scatter writes pair[k] = (user,item) per CSR slot for BOTH sides;
// all downstream kernels (matvec, user, ent) work in CSR-slot order, so
// rel/rtype are produced contiguous and the aggregation loops stream them.
// ---------------------------------------------------------------------------
__global__ __launch_bounds__(256) void k_hist(
    const int* __restrict__ ui, const int* __restrict__ ii,
    int* __restrict__ deg_u, int* __restrict__ deg_i)
{
  int e = blockIdx.x*256 + threadIdx.x;
  if (e >= NEDGE) return;
  atomicAdd(&deg_u[ui[e]], 1);
  atomicAdd(&deg_i[ii[e]], 1);
}

// Pass 1: per-block local exclusive scan of an 8192-elem tile + tile total.
__global__ __launch_bounds__(1024) void k_scan_part(
    const int* __restrict__ deg_u, int* __restrict__ off_u,
    const int* __restrict__ deg_i, int* __restrict__ off_i,
    int* __restrict__ part)
{
  __shared__ int wsum[16];
  const int b = blockIdx.x;
  const int t = threadIdx.x, lane = t & 63, wv = t >> 6;

  const int* deg; int* off; int n, base;
  if (b < NBU){ deg = deg_u; off = off_u; n = NUSR; base = b*8192; }
  else        { deg = deg_i; off = off_i; n = NENT; base = (b-NBU)*8192; }

  int loc[8]; int tsum = 0;
  const int i0 = base + t*8;
  #pragma unroll
  for (int j = 0; j < 8; j++){
    int i = i0 + j; int v = (i < n) ? deg[i] : 0;
    loc[j] = tsum; tsum += v;
  }
  int x = tsum;                           // inclusive wave scan
  #pragma unroll
  for (int d = 1; d < 64; d <<= 1){
    int y = __shfl_up(x, d);
    if (lane >= d) x += y;
  }
  if (lane == 63) wsum[wv] = x;
  __syncthreads();
  int wpre = 0, tot = 0;
  #pragma unroll
  for (int w2 = 0; w2 < 16; w2++){
    int s = wsum[w2];
    if (w2 < wv) wpre += s;
    tot += s;
  }
  int tbase = wpre + (x - tsum);          // exclusive thread base (local)
  #pragma unroll
  for (int j = 0; j < 8; j++){
    int i = i0 + j;
    if (i < n) off[i] = tbase + loc[j];
  }
  if (t == 0) part[b] = tot;
}

// Pass 2: add segment-local prefix of tile totals; write array totals.
__global__ __launch_bounds__(1024) void k_scan_add(
    int* __restrict__ off_u, int* __restrict__ off_i,
    const int* __restrict__ part)
{
  __shared__ int sp[NBT];
  const int b = blockIdx.x;
  const int t = threadIdx.x;
  if (t < NBT) sp[t] = part[t];
  __syncthreads();

  int* off; int n, base, segbeg;
  if (b < NBU){ off = off_u; n = NUSR; base = b*8192; segbeg = 0; }
  else        { off = off_i; n = NENT; base = (b-NBU)*8192; segbeg = NBU; }

  int pre = 0;
  for (int j = segbeg; j < b; j++) pre += sp[j];

  if (pre != 0){
    const int i0 = base + t*8;
    #pragma unroll
    for (int j = 0; j < 8; j++){
      int i = i0 + j;
      if (i < n) off[i] += pre;
    }
  }
  if (b == 0 && t == 0){
    int tu = 0; for (int j = 0; j < NBU; j++) tu += sp[j];
    int ti = 0; for (int j = NBU; j < NBT; j++) ti += sp[j];
    off_u[NUSR] = tu;
    off_i[NENT] = ti;
  }
}

__global__ __launch_bounds__(256) void k_scatter(
    const int* __restrict__ ui, const int* __restrict__ ii,
    const int* __restrict__ off_u, const int* __restrict__ off_i,
    int* __restrict__ cur_u, int* __restrict__ cur_i,
    int2* __restrict__ pair_u, int2* __restrict__ pair_i)
{
  int e = blockIdx.x*256 + threadIdx.x;
  if (e >= NEDGE) return;
  int u = ui[e], it = ii[e];
  int p = atomicAdd(&cur_u[u],  1); pair_u[off_u[u]  + p] = make_int2(u, it);
  int q = atomicAdd(&cur_i[it], 1); pair_i[off_i[it] + q] = make_int2(u, it);
}

// ---------------------------------------------------------------------------
// Per-slot 128->64 matvec via MFMA with 3-way bf16 truncation split (exact
// mantissa tiling; dropped terms ~2^-24 rel, same order as f32 rounding).
// Processes CSR SLOTS: row indices come from pair[slot], outputs rel[slot]
// and rtype[slot] contiguous. SWAP picks which pair field feeds A (concat
// order: ui-direction A=user=.x; iu-direction A=item=.y).
// Block: 512 threads = 8 waves, 128 slots (16/wave).
// ---------------------------------------------------------------------------
template<int WITH_ARGMAX, int SWAP>
__global__ __launch_bounds__(512,4) void k_matvec(
    const float* __restrict__ rowsA, const float* __restrict__ rowsB,
    const int2* __restrict__ pair,
    const float* __restrict__ lat,
    const float* __restrict__ Ww, const float* __restrict__ Wb,
    float* __restrict__ rel, int* __restrict__ rtype)
{
  // W planes: hi @0, mid @16384, lo @32768 (each 64 rows x 256B, swizzled).
  // After the post-K-loop barrier this region is reused as the per-wave
  // transpose buffer (8 waves x 16 x 68 f32 = 34816B <= 49152B).
  __shared__ __align__(16) char smem[49152];
  __shared__ float lat_lds[192];

  const int t  = threadIdx.x;
  const int e0 = blockIdx.x * 128;

  // ---- stage W (f32 [64][128]) as 3 swizzled bf16 planes: byte ^= (row&7)<<4
  {
    const int n  = t >> 3;              // W row (out dim)
    const int kb = (t & 7) * 16;        // f32 elem base within row
    const float4* s4 = (const float4*)(Ww + n*128 + kb);
    float4 q0 = s4[0], q1 = s4[1], q2 = s4[2], q3 = s4[3];
    float xs[16] = {q0.x,q0.y,q0.z,q0.w, q1.x,q1.y,q1.z,q1.w,
                    q2.x,q2.y,q2.z,q2.w, q3.x,q3.y,q3.z,q3.w};
    unsigned uh[8], um[8], ul[8];
    #pragma unroll
    for (int p = 0; p < 8; p++){
      float a = xs[2*p], b = xs[2*p+1];
      unsigned ua = __float_as_uint(a), ub = __float_as_uint(b);
      uh[p] = (ua >> 16) | (ub & 0xffff0000u);
      float ra = a - __uint_as_float(ua & 0xffff0000u);
      float rb = b - __uint_as_float(ub & 0xffff0000u);
      unsigned va = __float_as_uint(ra), vb = __float_as_uint(rb);
      um[p] = (va >> 16) | (vb & 0xffff0000u);
      float sa = ra - __uint_as_float(va & 0xffff0000u);
      float sb = rb - __uint_as_float(vb & 0xffff0000u);
      ul[p] = (__float_as_uint(sa) >> 16) | (__float_as_uint(sb) & 0xffff0000u);
    }
    char* dh = smem + n*256;
    const unsigned sw = (unsigned)((n & 7) << 4);
    const unsigned b0 = ((unsigned)(kb*2))      ^ sw;
    const unsigned b1 = ((unsigned)(kb*2 + 16)) ^ sw;
    *(uint4*)(dh + b0)         = make_uint4(uh[0],uh[1],uh[2],uh[3]);
    *(uint4*)(dh + b1)         = make_uint4(uh[4],uh[5],uh[6],uh[7]);
    *(uint4*)(dh + 16384 + b0) = make_uint4(um[0],um[1],um[2],um[3]);
    *(uint4*)(dh + 16384 + b1) = make_uint4(um[4],um[5],um[6],um[7]);
    *(uint4*)(dh + 32768 + b0) = make_uint4(ul[0],ul[1],ul[2],ul[3]);
    *(uint4*)(dh + 32768 + b1) = make_uint4(ul[4],ul[5],ul[6],ul[7]);
  }
  if (WITH_ARGMAX && t < 192) lat_lds[t] = lat[t];
  __syncthreads();

  const int w = t >> 6, l = t & 63;
  const int g = l >> 4, c = l & 15;

  const int sl = min(e0 + w*16 + c, NEDGE-1);
  const int2 pr = pair[sl];
  const int ia = SWAP ? pr.y : pr.x;
  const int ib = SWAP ? pr.x : pr.y;
  const float* pa = rowsA + (size_t)ia*64 + g*8;
  const float* pb = rowsB + (size_t)ib*64 + g*8;

  f32x4 acc[4];
  #pragma unroll
  for (int nt = 0; nt < 4; nt++){
    float bv = Wb[nt*16 + c];           // bias folded into C-init
    f32x4 a = {bv, bv, bv, bv};
    acc[nt] = a;
  }

  const unsigned sw = (unsigned)((c & 7) << 4);
  #pragma unroll
  for (int kk = 0; kk < 4; kk++){       // K=128 in 4 MFMA steps of 32
    const float* src = (kk < 2) ? (pa + (kk & 1)*32) : (pb + (kk & 1)*32);
    float4 x0 = *(const float4*)src;
    float4 x1 = *(const float4*)(src + 4);
    // 3-way truncation split
    float xsv[8] = {x0.x,x0.y,x0.z,x0.w, x1.x,x1.y,x1.z,x1.w};
    union { unsigned u[4]; bf16x8 v; } H, M, L;
    #pragma unroll
    for (int p = 0; p < 4; p++){
      float a = xsv[2*p], b = xsv[2*p+1];
      unsigned ua = __float_as_uint(a), ub = __float_as_uint(b);
      H.u[p] = (ua >> 16) | (ub & 0xffff0000u);
      float ra = a - __uint_as_float(ua & 0xffff0000u);
      float rb = b - __uint_as_float(ub & 0xffff0000u);
      unsigned va = __float_as_uint(ra), vb = __float_as_uint(rb);
      M.u[p] = (va >> 16) | (vb & 0xffff0000u);
      float sa = ra - __uint_as_float(va & 0xffff0000u);
      float sb = rb - __uint_as_float(vb & 0xffff0000u);
      L.u[p] = (__float_as_uint(sa) >> 16) | (__float_as_uint(sb) & 0xffff0000u);
    }
    bf16x8 a0 = H.v, a1 = M.v, a2 = L.v;
    const unsigned xoff = ((unsigned)(kk*64 + g*16)) ^ sw;
    #pragma unroll
    for (int nt = 0; nt < 4; nt++){
      const char* base = smem + (unsigned)((nt*16 + c)*256) + xoff;
      bf16x8 b0 = *(const bf16x8*)base;
      bf16x8 b1 = *(const bf16x8*)(base + 16384);
      bf16x8 b2 = *(const bf16x8*)(base + 32768);
      // smallest-magnitude terms first for accumulation
      acc[nt] = __builtin_amdgcn_mfma_f32_16x16x32_bf16(a0, b2, acc[nt], 0, 0, 0);
      acc[nt] = __builtin_amdgcn_mfma_f32_16x16x32_bf16(a1, b1, acc[nt], 0, 0, 0);
      acc[nt] = __builtin_amdgcn_mfma_f32_16x16x32_bf16(a2, b0, acc[nt], 0, 0, 0);
      acc[nt] = __builtin_amdgcn_mfma_f32_16x16x32_bf16(a0, b1, acc[nt], 0, 0, 0);
      acc[nt] = __builtin_amdgcn_mfma_f32_16x16x32_bf16(a1, b0, acc[nt], 0, 0, 0);
      acc[nt] = __builtin_amdgcn_mfma_f32_16x16x32_bf16(a0, b0, acc[nt], 0, 0, 0);
    }
  }

  // leaky_relu(0.01)
  #pragma unroll
  for (int nt = 0; nt < 4; nt++)
    #pragma unroll
    for (int r = 0; r < 4; r++){
      float v = acc[nt][r];
      acc[nt][r] = v > 0.f ? v : 0.01f*v;
    }

  // argmax over latent scores, straight from f32 accumulators
  if (WITH_ARGMAX){
    int rt[4];
    #pragma unroll
    for (int r = 0; r < 4; r++){
      float s0 = 0.f, s1 = 0.f, s2 = 0.f;
      #pragma unroll
      for (int nt = 0; nt < 4; nt++){
        float a = acc[nt][r];
        s0 += a * lat_lds[      nt*16 + c];
        s1 += a * lat_lds[ 64 + nt*16 + c];
        s2 += a * lat_lds[128 + nt*16 + c];
      }
      #pragma unroll
      for (int m = 1; m < 16; m <<= 1){   // reduce across out-dims (lane&15)
        s0 += __shfl_xor(s0, m);
        s1 += __shfl_xor(s1, m);
        s2 += __shfl_xor(s2, m);
      }
      int bf = 0; float bs = s0;
      if (s1 > bs){ bs = s1; bf = 1; }   // strict > : first-max like jnp.argmax
      if (s2 > bs){ bs = s2; bf = 2; }
      rt[r] = bf;
    }
    if (c == 0){
      int eb = e0 + w*16 + g*4;
      if (eb < NEDGE)
        *(int4*)(rtype + eb) = make_int4(rt[0], rt[1], rt[2], rt[3]);
    }
  }

  // All waves have finished reading the W planes after this barrier;
  // smem is then reused as the per-wave transpose buffer.
  __syncthreads();
  float* tb = (float*)smem + w*1088;    // [16][68] f32, 16B-aligned rows
  #pragma unroll
  for (int nt = 0; nt < 4; nt++)
    #pragma unroll
    for (int r = 0; r < 4; r++)
      tb[(g*4 + r)*68 + nt*16 + c] = acc[nt][r];

  #pragma unroll
  for (int r = 0; r < 4; r++){
    int g2 = l + 64*r;
    int el = g2 >> 4, c4 = (g2 & 15) << 2;
    int er = e0 + w*16 + el;
    if (er < NEDGE)
      *(float4*)(rel + (size_t)er*64 + c4) = *(const float4*)&tb[el*68 + c4];
  }
}

// ---------------------------------------------------------------------------
// User side, one wave per user, 4 edge-groups x 16 lanes (f32x4 dim slice).
// All per-slot streams (pair, rtype, rel) are CSR-contiguous; the only
// gather is the depth-1 ent-row read.
// ---------------------------------------------------------------------------
__global__ __launch_bounds__(256) void k_user(
    const float* __restrict__ ent, const float* __restrict__ usr,
    const float* __restrict__ w3,
    const int2* __restrict__ pair_u, const int* __restrict__ rtype,
    const float* __restrict__ rel,
    const int* __restrict__ off_u, float* __restrict__ out_user)
{
  const int l = threadIdx.x & 63;
  const int u = blockIdx.x*4 + (threadIdx.x >> 6);
  if (u >= NUSR) return;
  const int g = l >> 4, c = l & 15;
  const int beg = off_u[u], end = off_u[u+1];

  const f32x4 z = {0.f,0.f,0.f,0.f};
  f32x4 s0 = z, s1 = z, s2 = z;
  int c0 = 0, c1 = 0, c2 = 0;
  for (int k = beg + g; k < end; k += 4){
    int item = pair_u[k].y;
    int f = rtype[k];
    f32x4 ip = *(const f32x4*)(ent + (size_t)item*64 + (c<<2));
    if (f == 0){ s0 += ip; c0++; }
    else if (f == 1){ s1 += ip; c1++; }
    else { s2 += ip; c2++; }
  }
  // cross-group combine (groups hold disjoint edge subsets)
  #pragma unroll
  for (int m = 16; m < 64; m <<= 1){
    #pragma unroll
    for (int j = 0; j < 4; j++){
      s0[j] += __shfl_xor(s0[j], m);
      s1[j] += __shfl_xor(s1[j], m);
      s2[j] += __shfl_xor(s2[j], m);
    }
    c0 += __shfl_xor(c0, m);
    c1 += __shfl_xor(c1, m);
    c2 += __shfl_xor(c2, m);
  }
  const float d0 = fmaxf((float)c0, 1.f);
  const float d1 = fmaxf((float)c1, 1.f);
  const float d2 = fmaxf((float)c2, 1.f);

  f32x4 a0 = z, a1 = z, a2 = z;
  for (int k = beg + g; k < end; k += 4){
    int item = pair_u[k].y;
    int f = rtype[k];
    f32x4 ip = *(const f32x4*)(ent + (size_t)item*64 + (c<<2));
    f32x4 rv = *(const f32x4*)(rel + (size_t)k*64 + (c<<2));
    f32x4 sf = (f == 0) ? s0 : ((f == 1) ? s1 : s2);
    float dd = (f == 0) ? d0 : ((f == 1) ? d1 : d2);
    float p = rv[0]*sf[0] + rv[1]*sf[1] + rv[2]*sf[2] + rv[3]*sf[3];
    #pragma unroll
    for (int m = 1; m < 16; m <<= 1) p += __shfl_xor(p, m);
    float sim = p / dd;                 // dot(rel, u_) with mean folded in
    f32x4 tv = ip * sim;
    if (f == 0) a0 += tv; else if (f == 1) a1 += tv; else a2 += tv;
  }
  #pragma unroll
  for (int m = 16; m < 64; m <<= 1){
    #pragma unroll
    for (int j = 0; j < 4; j++){
      a0[j] += __shfl_xor(a0[j], m);
      a1[j] += __shfl_xor(a1[j], m);
      a2[j] += __shfl_xor(a2[j], m);
    }
  }

  float wa = w3[0], wb = w3[1], wc = w3[2];
  float mx = fmaxf(wa, fmaxf(wb, wc));
  float ea = expf(wa-mx), eb = expf(wb-mx), ec = expf(wc-mx);
  float inv = 1.f/(ea+eb+ec);
  f32x4 ue = *(const f32x4*)(usr + (size_t)u*64 + (c<<2));
  f32x4 av[3] = {a0, a1, a2};
  float dv[3] = {d0, d1, d2}, wv[3] = {ea*inv, eb*inv, ec*inv};
  f32x4 o = z;
  #pragma unroll
  for (int f = 0; f < 3; f++){
    f32x4 v = av[f] / dv[f];
    float n2 = v[0]*v[0] + v[1]*v[1] + v[2]*v[2] + v[3]*v[3];
    #pragma unroll
    for (int m = 1; m < 16; m <<= 1) n2 += __shfl_xor(n2, m);
    float n = sqrtf(n2);
    float fac = (n2/(n2 + 1.f)) / fmaxf(n, 1e-12f);
    o += (v * fac + ue) * wv[f];
  }
  if (g == 0)
    *(f32x4*)(out_user + (size_t)u*64 + (c<<2)) = o;
}

// ---------------------------------------------------------------------------
// Entity side, one wave per entity, same 4x16 layout.
// ---------------------------------------------------------------------------
__global__ __launch_bounds__(256) void k_ent(
    const float* __restrict__ ent, const float* __restrict__ usr,
    const int2* __restrict__ pair_i, const float* __restrict__ rel,
    const int* __restrict__ off_i, float* __restrict__ out_ent)
{
  const int l = threadIdx.x & 63;
  const int i = blockIdx.x*4 + (threadIdx.x >> 6);
  if (i >= NENT) return;
  const int g = l >> 4, c = l & 15;
  const int beg = off_i[i], end = off_i[i+1];

  const f32x4 z = {0.f,0.f,0.f,0.f};
  f32x4 s = z;
  for (int k = beg + g; k < end; k += 4){
    int us = pair_i[k].x;
    s += *(const f32x4*)(usr + (size_t)us*64 + (c<<2));
  }
  #pragma unroll
  for (int m = 16; m < 64; m <<= 1){
    #pragma unroll
    for (int j = 0; j < 4; j++) s[j] += __shfl_xor(s[j], m);
  }
  const float d = fmaxf((float)(end - beg), 1.f);

  f32x4 a = z;
  for (int k = beg + g; k < end; k += 4){
    int us = pair_i[k].x;
    f32x4 up = *(const f32x4*)(usr + (size_t)us*64 + (c<<2));
    f32x4 rv = *(const f32x4*)(rel + (size_t)k*64 + (c<<2));
    float p = rv[0]*s[0] + rv[1]*s[1] + rv[2]*s[2] + rv[3]*s[3];
    #pragma unroll
    for (int m = 1; m < 16; m <<= 1) p += __shfl_xor(p, m);
    a += up * (p / d);
  }
  #pragma unroll
  for (int m = 16; m < 64; m <<= 1){
    #pragma unroll
    for (int j = 0; j < 4; j++) a[j] += __shfl_xor(a[j], m);
  }

  f32x4 v = a / d;
  float n2 = v[0]*v[0] + v[1]*v[1] + v[2]*v[2] + v[3]*v[3];
  #pragma unroll
  for (int m = 1; m < 16; m <<= 1) n2 += __shfl_xor(n2, m);
  float n = sqrtf(n2);
  float fac = (n2/(n2 + 1.f)) / fmaxf(n, 1e-12f);
  f32x4 ev = *(const f32x4*)(ent + (size_t)i*64 + (c<<2));
  if (g == 0)
    *(f32x4*)(out_ent + (size_t)i*64 + (c<<2)) = v * fac + ev;
}

// ---------------------------------------------------------------------------
// Workspace layout (f32 element offsets). Total: ~141.6 MB.
// rel_ui and rel_iu SHARE one buffer (disjoint lifetimes given launch order
// matvec<ui> -> k_user -> matvec<iu> -> k_ent); working set fits L3.
//   rel     f32 [E*64]   @ 0            (128 MB)
//   zero-block           @ 32,000,000:  deg_u(100k) cur_u(100k) deg_i(200k) cur_i(200k)
//   off_u   [U+1]        @ 32,600,000
//   off_i   [ENT+1]      @ 32,700,004
//   pair_u  int2 [E]     @ 32,900,008   (byte offset %8 == 0)
//   pair_i  int2 [E]     @ 33,900,008
//   rtype   [E]          @ 34,900,008
//   part    [NBT]        @ 35,400,008
// ---------------------------------------------------------------------------
extern "C" void kernel_launch(void* const* d_in, const int* in_sizes, int n_in,
                              void* d_out, int out_size, void* d_ws, size_t ws_size,
                              hipStream_t stream) {
  const float* ent = (const float*)d_in[0];
  const float* usr = (const float*)d_in[1];
  const float* lat = (const float*)d_in[2];
  const int*   ui  = (const int*)d_in[3];
  const int*   ii  = (const int*)d_in[4];
  const float* Ww  = (const float*)d_in[5];
  const float* Wb  = (const float*)d_in[6];
  const float* Wiw = (const float*)d_in[7];
  const float* Wib = (const float*)d_in[8];
  const float* w3  = (const float*)d_in[9];

  float* ws = (float*)d_ws;
  float* rel    = ws;
  int*   deg_u  = (int*)(ws + 32000000ull);
  int*   cur_u  = deg_u + 100000;
  int*   deg_i  = cur_u + 100000;
  int*   cur_i  = deg_i + 200000;
  int*   off_u  = (int*)(ws + 32600000ull);
  int*   off_i  = (int*)(ws + 32700004ull);
  int2*  pair_u = (int2*)(ws + 32900008ull);
  int2*  pair_i = (int2*)(ws + 33900008ull);
  int*   rtype  = (int*)(ws + 34900008ull);
  int*   part   = (int*)(ws + 35400008ull);

  float* out_ent  = (float*)d_out;
  float* out_user = (float*)d_out + (size_t)NENT*64;

  hipMemsetAsync(deg_u, 0, 600000*sizeof(int), stream);   // deg+cur, both sides

  k_hist<<<1954, 256, 0, stream>>>(ui, ii, deg_u, deg_i);
  k_scan_part<<<NBT, 1024, 0, stream>>>(deg_u, off_u, deg_i, off_i, part);
  k_scan_add<<<NBT, 1024, 0, stream>>>(off_u, off_i, part);
  k_scatter<<<1954, 256, 0, stream>>>(ui, ii, off_u, off_i,
                                      cur_u, cur_i, pair_u, pair_i);

  // relation_ui = leaky(concat([user, item]) @ Ww^T + b), + argmax -> rtype
  k_matvec<1,0><<<3907, 512, 0, stream>>>(usr, ent, pair_u, lat, Ww, Wb,
                                          rel, rtype);
  k_user<<<25000, 256, 0, stream>>>(ent, usr, w3, pair_u, rtype, rel,
                                    off_u, out_user);
  // relation_iu = leaky(concat([item, user]) @ Wiw^T + b)  (reuses rel buffer)
  k_matvec<0,1><<<3907, 512, 0, stream>>>(ent, usr, pair_i, lat, Wiw, Wib,
                                          rel, rtype);
  k_ent<<<50000, 256, 0, stream>>>(ent, usr, pair_i, rel,
                                   off_i, out_ent);
}

// Round 5
// 503.096 us; speedup vs baseline: 2.3951x; 1.1246x over previous
//
#include <hip/hip_runtime.h>
#include <stdint.h>

#define NEDGE 500000
#define NUSR  100000
#define NENT  200000

// scan tiling: 8192 elems/block; 13 blocks cover NUSR, 25 cover NENT
#define NBU 13
#define NBI 25
#define NBT 38

typedef __attribute__((ext_vector_type(8))) short bf16x8;
typedef __attribute__((ext_vector_type(4))) float f32x4;

// ---------------------------------------------------------------------------
// CSR build: histogram -> two-pass parallel scan -> cursor scatter.
// k_scatter writes pair[k] = (user,item) per CSR slot for BOTH sides;
// all downstream kernels (matvec, user, ent) work in CSR-slot order, so
// rel/rtype are produced contiguous and the aggregation loops stream them.
// ---------------------------------------------------------------------------
__global__ __launch_bounds__(256) void k_hist(
    const int* __restrict__ ui, const int* __restrict__ ii,
    int* __restrict__ deg_u, int* __restrict__ deg_i)
{
  int e = blockIdx.x*256 + threadIdx.x;
  if (e >= NEDGE) return;
  atomicAdd(&deg_u[ui[e]], 1);
  atomicAdd(&deg_i[ii[e]], 1);
}

// Pass 1: per-block local exclusive scan of an 8192-elem tile + tile total.
__global__ __launch_bounds__(1024) void k_scan_part(
    const int* __restrict__ deg_u, int* __restrict__ off_u,
    const int* __restrict__ deg_i, int* __restrict__ off_i,
    int* __restrict__ part)
{
  __shared__ int wsum[16];
  const int b = blockIdx.x;
  const int t = threadIdx.x, lane = t & 63, wv = t >> 6;

  const int* deg; int* off; int n, base;
  if (b < NBU){ deg = deg_u; off = off_u; n = NUSR; base = b*8192; }
  else        { deg = deg_i; off = off_i; n = NENT; base = (b-NBU)*8192; }

  int loc[8]; int tsum = 0;
  const int i0 = base + t*8;
  #pragma unroll
  for (int j = 0; j < 8; j++){
    int i = i0 + j; int v = (i < n) ? deg[i] : 0;
    loc[j] = tsum; tsum += v;
  }
  int x = tsum;                           // inclusive wave scan
  #pragma unroll
  for (int d = 1; d < 64; d <<= 1){
    int y = __shfl_up(x, d);
    if (lane >= d) x += y;
  }
  if (lane == 63) wsum[wv] = x;
  __syncthreads();
  int wpre = 0, tot = 0;
  #pragma unroll
  for (int w2 = 0; w2 < 16; w2++){
    int s = wsum[w2];
    if (w2 < wv) wpre += s;
    tot += s;
  }
  int tbase = wpre + (x - tsum);          // exclusive thread base (local)
  #pragma unroll
  for (int j = 0; j < 8; j++){
    int i = i0 + j;
    if (i < n) off[i] = tbase + loc[j];
  }
  if (t == 0) part[b] = tot;
}

// Pass 2: add segment-local prefix of tile totals; write array totals.
__global__ __launch_bounds__(1024) void k_scan_add(
    int* __restrict__ off_u, int* __restrict__ off_i,
    const int* __restrict__ part)
{
  __shared__ int sp[NBT];
  const int b = blockIdx.x;
  const int t = threadIdx.x;
  if (t < NBT) sp[t] = part[t];
  __syncthreads();

  int* off; int n, base, segbeg;
  if (b < NBU){ off = off_u; n = NUSR; base = b*8192; segbeg = 0; }
  else        { off = off_i; n = NENT; base = (b-NBU)*8192; segbeg = NBU; }

  int pre = 0;
  for (int j = segbeg; j < b; j++) pre += sp[j];

  if (pre != 0){
    const int i0 = base + t*8;
    #pragma unroll
    for (int j = 0; j < 8; j++){
      int i = i0 + j;
      if (i < n) off[i] += pre;
    }
  }
  if (b == 0 && t == 0){
    int tu = 0; for (int j = 0; j < NBU; j++) tu += sp[j];
    int ti = 0; for (int j = NBU; j < NBT; j++) ti += sp[j];
    off_u[NUSR] = tu;
    off_i[NENT] = ti;
  }
}

__global__ __launch_bounds__(256) void k_scatter(
    const int* __restrict__ ui, const int* __restrict__ ii,
    const int* __restrict__ off_u, const int* __restrict__ off_i,
    int* __restrict__ cur_u, int* __restrict__ cur_i,
    int2* __restrict__ pair_u, int2* __restrict__ pair_i)
{
  int e = blockIdx.x*256 + threadIdx.x;
  if (e >= NEDGE) return;
  int u = ui[e], it = ii[e];
  int p = atomicAdd(&cur_u[u],  1); pair_u[off_u[u]  + p] = make_int2(u, it);
  int q = atomicAdd(&cur_i[it], 1); pair_i[off_i[it] + q] = make_int2(u, it);
}

// ---------------------------------------------------------------------------
// Per-slot 128->64 matvec via MFMA with 3-way bf16 truncation split (exact
// mantissa tiling; dropped terms ~2^-24 rel, same order as f32 rounding).
// Processes CSR SLOTS: row indices come from pair[slot], outputs rel[slot]
// and rtype[slot] contiguous. SWAP picks which pair field feeds A (concat
// order: ui-direction A=user=.x; iu-direction A=item=.y).
// Block: 512 threads = 8 waves, 128 slots (16/wave).
// ---------------------------------------------------------------------------
template<int WITH_ARGMAX, int SWAP>
__global__ __launch_bounds__(512,4) void k_matvec(
    const float* __restrict__ rowsA, const float* __restrict__ rowsB,
    const int2* __restrict__ pair,
    const float* __restrict__ lat,
    const float* __restrict__ Ww, const float* __restrict__ Wb,
    float* __restrict__ rel, int* __restrict__ rtype)
{
  // W planes: hi @0, mid @16384, lo @32768 (each 64 rows x 256B, swizzled).
  // After the post-K-loop barrier this region is reused as the per-wave
  // transpose buffer (8 waves x 16 x 68 f32 = 34816B <= 49152B).
  __shared__ __align__(16) char smem[49152];
  __shared__ float lat_lds[192];

  const int t  = threadIdx.x;
  const int e0 = blockIdx.x * 128;

  // ---- stage W (f32 [64][128]) as 3 swizzled bf16 planes: byte ^= (row&7)<<4
  {
    const int n  = t >> 3;              // W row (out dim)
    const int kb = (t & 7) * 16;        // f32 elem base within row
    const float4* s4 = (const float4*)(Ww + n*128 + kb);
    float4 q0 = s4[0], q1 = s4[1], q2 = s4[2], q3 = s4[3];
    float xs[16] = {q0.x,q0.y,q0.z,q0.w, q1.x,q1.y,q1.z,q1.w,
                    q2.x,q2.y,q2.z,q2.w, q3.x,q3.y,q3.z,q3.w};
    unsigned uh[8], um[8], ul[8];
    #pragma unroll
    for (int p = 0; p < 8; p++){
      float a = xs[2*p], b = xs[2*p+1];
      unsigned ua = __float_as_uint(a), ub = __float_as_uint(b);
      uh[p] = (ua >> 16) | (ub & 0xffff0000u);
      float ra = a - __uint_as_float(ua & 0xffff0000u);
      float rb = b - __uint_as_float(ub & 0xffff0000u);
      unsigned va = __float_as_uint(ra), vb = __float_as_uint(rb);
      um[p] = (va >> 16) | (vb & 0xffff0000u);
      float sa = ra - __uint_as_float(va & 0xffff0000u);
      float sb = rb - __uint_as_float(vb & 0xffff0000u);
      ul[p] = (__float_as_uint(sa) >> 16) | (__float_as_uint(sb) & 0xffff0000u);
    }
    char* dh = smem + n*256;
    const unsigned sw = (unsigned)((n & 7) << 4);
    const unsigned b0 = ((unsigned)(kb*2))      ^ sw;
    const unsigned b1 = ((unsigned)(kb*2 + 16)) ^ sw;
    *(uint4*)(dh + b0)         = make_uint4(uh[0],uh[1],uh[2],uh[3]);
    *(uint4*)(dh + b1)         = make_uint4(uh[4],uh[5],uh[6],uh[7]);
    *(uint4*)(dh + 16384 + b0) = make_uint4(um[0],um[1],um[2],um[3]);
    *(uint4*)(dh + 16384 + b1) = make_uint4(um[4],um[5],um[6],um[7]);
    *(uint4*)(dh + 32768 + b0) = make_uint4(ul[0],ul[1],ul[2],ul[3]);
    *(uint4*)(dh + 32768 + b1) = make_uint4(ul[4],ul[5],ul[6],ul[7]);
  }
  if (WITH_ARGMAX && t < 192) lat_lds[t] = lat[t];
  __syncthreads();

  const int w = t >> 6, l = t & 63;
  const int g = l >> 4, c = l & 15;

  const int sl = min(e0 + w*16 + c, NEDGE-1);
  const int2 pr = pair[sl];
  const int ia = SWAP ? pr.y : pr.x;
  const int ib = SWAP ? pr.x : pr.y;
  const float* pa = rowsA + (size_t)ia*64 + g*8;
  const float* pb = rowsB + (size_t)ib*64 + g*8;

  f32x4 acc[4];
  #pragma unroll
  for (int nt = 0; nt < 4; nt++){
    float bv = Wb[nt*16 + c];           // bias folded into C-init
    f32x4 a = {bv, bv, bv, bv};
    acc[nt] = a;
  }

  const unsigned sw = (unsigned)((c & 7) << 4);
  #pragma unroll
  for (int kk = 0; kk < 4; kk++){       // K=128 in 4 MFMA steps of 32
    const float* src = (kk < 2) ? (pa + (kk & 1)*32) : (pb + (kk & 1)*32);
    float4 x0 = *(const float4*)src;
    float4 x1 = *(const float4*)(src + 4);
    // 3-way truncation split
    float xsv[8] = {x0.x,x0.y,x0.z,x0.w, x1.x,x1.y,x1.z,x1.w};
    union { unsigned u[4]; bf16x8 v; } H, M, L;
    #pragma unroll
    for (int p = 0; p < 4; p++){
      float a = xsv[2*p], b = xsv[2*p+1];
      unsigned ua = __float_as_uint(a), ub = __float_as_uint(b);
      H.u[p] = (ua >> 16) | (ub & 0xffff0000u);
      float ra = a - __uint_as_float(ua & 0xffff0000u);
      float rb = b - __uint_as_float(ub & 0xffff0000u);
      unsigned va = __float_as_uint(ra), vb = __float_as_uint(rb);
      M.u[p] = (va >> 16) | (vb & 0xffff0000u);
      float sa = ra - __uint_as_float(va & 0xffff0000u);
      float sb = rb - __uint_as_float(vb & 0xffff0000u);
      L.u[p] = (__float_as_uint(sa) >> 16) | (__float_as_uint(sb) & 0xffff0000u);
    }
    bf16x8 a0 = H.v, a1 = M.v, a2 = L.v;
    const unsigned xoff = ((unsigned)(kk*64 + g*16)) ^ sw;
    #pragma unroll
    for (int nt = 0; nt < 4; nt++){
      const char* base = smem + (unsigned)((nt*16 + c)*256) + xoff;
      bf16x8 b0 = *(const bf16x8*)base;
      bf16x8 b1 = *(const bf16x8*)(base + 16384);
      bf16x8 b2 = *(const bf16x8*)(base + 32768);
      // smallest-magnitude terms first for accumulation
      acc[nt] = __builtin_amdgcn_mfma_f32_16x16x32_bf16(a0, b2, acc[nt], 0, 0, 0);
      acc[nt] = __builtin_amdgcn_mfma_f32_16x16x32_bf16(a1, b1, acc[nt], 0, 0, 0);
      acc[nt] = __builtin_amdgcn_mfma_f32_16x16x32_bf16(a2, b0, acc[nt], 0, 0, 0);
      acc[nt] = __builtin_amdgcn_mfma_f32_16x16x32_bf16(a0, b1, acc[nt], 0, 0, 0);
      acc[nt] = __builtin_amdgcn_mfma_f32_16x16x32_bf16(a1, b0, acc[nt], 0, 0, 0);
      acc[nt] = __builtin_amdgcn_mfma_f32_16x16x32_bf16(a0, b0, acc[nt], 0, 0, 0);
    }
  }

  // leaky_relu(0.01)
  #pragma unroll
  for (int nt = 0; nt < 4; nt++)
    #pragma unroll
    for (int r = 0; r < 4; r++){
      float v = acc[nt][r];
      acc[nt][r] = v > 0.f ? v : 0.01f*v;
    }

  // argmax over latent scores, straight from f32 accumulators
  if (WITH_ARGMAX){
    int rt[4];
    #pragma unroll
    for (int r = 0; r < 4; r++){
      float s0 = 0.f, s1 = 0.f, s2 = 0.f;
      #pragma unroll
      for (int nt = 0; nt < 4; nt++){
        float a = acc[nt][r];
        s0 += a * lat_lds[      nt*16 + c];
        s1 += a * lat_lds[ 64 + nt*16 + c];
        s2 += a * lat_lds[128 + nt*16 + c];
      }
      #pragma unroll
      for (int m = 1; m < 16; m <<= 1){   // reduce across out-dims (lane&15)
        s0 += __shfl_xor(s0, m);
        s1 += __shfl_xor(s1, m);
        s2 += __shfl_xor(s2, m);
      }
      int bf = 0; float bs = s0;
      if (s1 > bs){ bs = s1; bf = 1; }   // strict > : first-max like jnp.argmax
      if (s2 > bs){ bs = s2; bf = 2; }
      rt[r] = bf;
    }
    if (c == 0){
      int eb = e0 + w*16 + g*4;
      if (eb < NEDGE)
        *(int4*)(rtype + eb) = make_int4(rt[0], rt[1], rt[2], rt[3]);
    }
  }

  // All waves have finished reading the W planes after this barrier;
  // smem is then reused as the per-wave transpose buffer.
  __syncthreads();
  float* tb = (float*)smem + w*1088;    // [16][68] f32, 16B-aligned rows
  #pragma unroll
  for (int nt = 0; nt < 4; nt++)
    #pragma unroll
    for (int r = 0; r < 4; r++)
      tb[(g*4 + r)*68 + nt*16 + c] = acc[nt][r];

  #pragma unroll
  for (int r = 0; r < 4; r++){
    int g2 = l + 64*r;
    int el = g2 >> 4, c4 = (g2 & 15) << 2;
    int er = e0 + w*16 + el;
    if (er < NEDGE)
      *(float4*)(rel + (size_t)er*64 + c4) = *(const float4*)&tb[el*68 + c4];
  }
}

// ---------------------------------------------------------------------------
// User side: ONE 16-LANE GROUP PER USER (4 users/wave, 16 users/block).
// Lane c = dim-slice (f32x4). Pass-1 sums are group-local (zero shuffles);
// only the per-edge dot and the epilogue n2 need 4-step 16-lane reduces.
// All per-slot streams (pair, rtype, rel) are CSR-contiguous.
// ---------------------------------------------------------------------------
__global__ __launch_bounds__(256) void k_user(
    const float* __restrict__ ent, const float* __restrict__ usr,
    const float* __restrict__ w3,
    const int2* __restrict__ pair_u, const int* __restrict__ rtype,
    const float* __restrict__ rel,
    const int* __restrict__ off_u, float* __restrict__ out_user)
{
  const int t = threadIdx.x;
  const int c = t & 15;
  const int u = blockIdx.x*16 + (t >> 4);
  if (u >= NUSR) return;
  const int beg = off_u[u], end = off_u[u+1];

  const f32x4 z = {0.f,0.f,0.f,0.f};
  f32x4 s0 = z, s1 = z, s2 = z;
  int c0 = 0, c1 = 0, c2 = 0;
  for (int k = beg; k < end; k++){
    int item = pair_u[k].y;
    int f = rtype[k];
    f32x4 ip = *(const f32x4*)(ent + (size_t)item*64 + (c<<2));
    if (f == 0){ s0 += ip; c0++; }
    else if (f == 1){ s1 += ip; c1++; }
    else { s2 += ip; c2++; }
  }
  const float d0 = fmaxf((float)c0, 1.f);
  const float d1 = fmaxf((float)c1, 1.f);
  const float d2 = fmaxf((float)c2, 1.f);

  f32x4 a0 = z, a1 = z, a2 = z;
  for (int k = beg; k < end; k++){
    int item = pair_u[k].y;
    int f = rtype[k];
    f32x4 ip = *(const f32x4*)(ent + (size_t)item*64 + (c<<2));
    f32x4 rv = *(const f32x4*)(rel + (size_t)k*64 + (c<<2));
    f32x4 sf = (f == 0) ? s0 : ((f == 1) ? s1 : s2);
    float dd = (f == 0) ? d0 : ((f == 1) ? d1 : d2);
    float p = rv[0]*sf[0] + rv[1]*sf[1] + rv[2]*sf[2] + rv[3]*sf[3];
    #pragma unroll
    for (int m = 1; m < 16; m <<= 1) p += __shfl_xor(p, m);
    float sim = p / dd;                 // dot(rel, u_) with mean folded in
    f32x4 tv = ip * sim;
    if (f == 0) a0 += tv; else if (f == 1) a1 += tv; else a2 += tv;
  }

  float wa = w3[0], wb = w3[1], wc = w3[2];
  float mx = fmaxf(wa, fmaxf(wb, wc));
  float ea = expf(wa-mx), eb = expf(wb-mx), ec = expf(wc-mx);
  float inv = 1.f/(ea+eb+ec);
  f32x4 ue = *(const f32x4*)(usr + (size_t)u*64 + (c<<2));
  f32x4 av[3] = {a0, a1, a2};
  float dv[3] = {d0, d1, d2}, wv[3] = {ea*inv, eb*inv, ec*inv};
  f32x4 o = z;
  #pragma unroll
  for (int f = 0; f < 3; f++){
    f32x4 v = av[f] / dv[f];
    float n2 = v[0]*v[0] + v[1]*v[1] + v[2]*v[2] + v[3]*v[3];
    #pragma unroll
    for (int m = 1; m < 16; m <<= 1) n2 += __shfl_xor(n2, m);
    float n = sqrtf(n2);
    float fac = (n2/(n2 + 1.f)) / fmaxf(n, 1e-12f);
    o += (v * fac + ue) * wv[f];
  }
  *(f32x4*)(out_user + (size_t)u*64 + (c<<2)) = o;
}

// ---------------------------------------------------------------------------
// Entity side: one 16-lane group per entity (4/wave, 16/block).
// ---------------------------------------------------------------------------
__global__ __launch_bounds__(256) void k_ent(
    const float* __restrict__ ent, const float* __restrict__ usr,
    const int2* __restrict__ pair_i, const float* __restrict__ rel,
    const int* __restrict__ off_i, float* __restrict__ out_ent)
{
  const int t = threadIdx.x;
  const int c = t & 15;
  const int i = blockIdx.x*16 + (t >> 4);
  if (i >= NENT) return;
  const int beg = off_i[i], end = off_i[i+1];

  const f32x4 z = {0.f,0.f,0.f,0.f};
  f32x4 s = z;
  for (int k = beg; k < end; k++){
    int us = pair_i[k].x;
    s += *(const f32x4*)(usr + (size_t)us*64 + (c<<2));
  }
  const float d = fmaxf((float)(end - beg), 1.f);

  f32x4 a = z;
  for (int k = beg; k < end; k++){
    int us = pair_i[k].x;
    f32x4 up = *(const f32x4*)(usr + (size_t)us*64 + (c<<2));
    f32x4 rv = *(const f32x4*)(rel + (size_t)k*64 + (c<<2));
    float p = rv[0]*s[0] + rv[1]*s[1] + rv[2]*s[2] + rv[3]*s[3];
    #pragma unroll
    for (int m = 1; m < 16; m <<= 1) p += __shfl_xor(p, m);
    a += up * (p / d);
  }

  f32x4 v = a / d;
  float n2 = v[0]*v[0] + v[1]*v[1] + v[2]*v[2] + v[3]*v[3];
  #pragma unroll
  for (int m = 1; m < 16; m <<= 1) n2 += __shfl_xor(n2, m);
  float n = sqrtf(n2);
  float fac = (n2/(n2 + 1.f)) / fmaxf(n, 1e-12f);
  f32x4 ev = *(const f32x4*)(ent + (size_t)i*64 + (c<<2));
  *(f32x4*)(out_ent + (size_t)i*64 + (c<<2)) = v * fac + ev;
}

// ---------------------------------------------------------------------------
// Workspace layout (f32 element offsets). Total: ~141.6 MB.
// rel_ui and rel_iu SHARE one buffer (disjoint lifetimes given launch order
// matvec<ui> -> k_user -> matvec<iu> -> k_ent); working set fits L3.
//   rel     f32 [E*64]   @ 0            (128 MB)
//   zero-block           @ 32,000,000:  deg_u(100k) cur_u(100k) deg_i(200k) cur_i(200k)
//   off_u   [U+1]        @ 32,600,000
//   off_i   [ENT+1]      @ 32,700,004
//   pair_u  int2 [E]     @ 32,900,008   (byte offset %8 == 0)
//   pair_i  int2 [E]     @ 33,900,008
//   rtype   [E]          @ 34,900,008
//   part    [NBT]        @ 35,400,008
// ---------------------------------------------------------------------------
extern "C" void kernel_launch(void* const* d_in, const int* in_sizes, int n_in,
                              void* d_out, int out_size, void* d_ws, size_t ws_size,
                              hipStream_t stream) {
  const float* ent = (const float*)d_in[0];
  const float* usr = (const float*)d_in[1];
  const float* lat = (const float*)d_in[2];
  const int*   ui  = (const int*)d_in[3];
  const int*   ii  = (const int*)d_in[4];
  const float* Ww  = (const float*)d_in[5];
  const float* Wb  = (const float*)d_in[6];
  const float* Wiw = (const float*)d_in[7];
  const float* Wib = (const float*)d_in[8];
  const float* w3  = (const float*)d_in[9];

  float* ws = (float*)d_ws;
  float* rel    = ws;
  int*   deg_u  = (int*)(ws + 32000000ull);
  int*   cur_u  = deg_u + 100000;
  int*   deg_i  = cur_u + 100000;
  int*   cur_i  = deg_i + 200000;
  int*   off_u  = (int*)(ws + 32600000ull);
  int*   off_i  = (int*)(ws + 32700004ull);
  int2*  pair_u = (int2*)(ws + 32900008ull);
  int2*  pair_i = (int2*)(ws + 33900008ull);
  int*   rtype  = (int*)(ws + 34900008ull);
  int*   part   = (int*)(ws + 35400008ull);

  float* out_ent  = (float*)d_out;
  float* out_user = (float*)d_out + (size_t)NENT*64;

  hipMemsetAsync(deg_u, 0, 600000*sizeof(int), stream);   // deg+cur, both sides

  k_hist<<<1954, 256, 0, stream>>>(ui, ii, deg_u, deg_i);
  k_scan_part<<<NBT, 1024, 0, stream>>>(deg_u, off_u, deg_i, off_i, part);
  k_scan_add<<<NBT, 1024, 0, stream>>>(off_u, off_i, part);
  k_scatter<<<1954, 256, 0, stream>>>(ui, ii, off_u, off_i,
                                      cur_u, cur_i, pair_u, pair_i);

  // relation_ui = leaky(concat([user, item]) @ Ww^T + b), + argmax -> rtype
  k_matvec<1,0><<<3907, 512, 0, stream>>>(usr, ent, pair_u, lat, Ww, Wb,
                                          rel, rtype);
  k_user<<<6250, 256, 0, stream>>>(ent, usr, w3, pair_u, rtype, rel,
                                   off_u, out_user);
  // relation_iu = leaky(concat([item, user]) @ Wiw^T + b)  (reuses rel buffer)
  k_matvec<0,1><<<3907, 512, 0, stream>>>(ent, usr, pair_i, lat, Wiw, Wib,
                                          rel, rtype);
  k_ent<<<12500, 256, 0, stream>>>(ent, usr, pair_i, rel,
                                   off_i, out_ent);
}

// Round 6
// 500.864 us; speedup vs baseline: 2.4057x; 1.0045x over previous
//
#include <hip/hip_runtime.h>
#include <stdint.h>

#define NEDGE 500000
#define NUSR  100000
#define NENT  200000

// scan tiling: 8192 elems/block; 13 blocks cover NUSR, 25 cover NENT
#define NBU 13
#define NBI 25
#define NBT 38

typedef __attribute__((ext_vector_type(8))) short bf16x8;
typedef __attribute__((ext_vector_type(4))) float f32x4;
typedef _Float16 f16;
typedef __attribute__((ext_vector_type(4))) _Float16 f16x4;
typedef __attribute__((ext_vector_type(8))) _Float16 f16x8;

// ---------------------------------------------------------------------------
// CSR build: histogram -> two-pass parallel scan -> cursor scatter.
// k_scatter writes pair[k] = (user,item) per CSR slot for BOTH sides;
// all downstream kernels (matvec, user, ent) work in CSR-slot order, so
// rel/rtype are produced contiguous and the aggregation loops stream them.
// ---------------------------------------------------------------------------
__global__ __launch_bounds__(256) void k_hist(
    const int* __restrict__ ui, const int* __restrict__ ii,
    int* __restrict__ deg_u, int* __restrict__ deg_i)
{
  int e = blockIdx.x*256 + threadIdx.x;
  if (e >= NEDGE) return;
  atomicAdd(&deg_u[ui[e]], 1);
  atomicAdd(&deg_i[ii[e]], 1);
}

// Pass 1: per-block local exclusive scan of an 8192-elem tile + tile total.
__global__ __launch_bounds__(1024) void k_scan_part(
    const int* __restrict__ deg_u, int* __restrict__ off_u,
    const int* __restrict__ deg_i, int* __restrict__ off_i,
    int* __restrict__ part)
{
  __shared__ int wsum[16];
  const int b = blockIdx.x;
  const int t = threadIdx.x, lane = t & 63, wv = t >> 6;

  const int* deg; int* off; int n, base;
  if (b < NBU){ deg = deg_u; off = off_u; n = NUSR; base = b*8192; }
  else        { deg = deg_i; off = off_i; n = NENT; base = (b-NBU)*8192; }

  int loc[8]; int tsum = 0;
  const int i0 = base + t*8;
  #pragma unroll
  for (int j = 0; j < 8; j++){
    int i = i0 + j; int v = (i < n) ? deg[i] : 0;
    loc[j] = tsum; tsum += v;
  }
  int x = tsum;                           // inclusive wave scan
  #pragma unroll
  for (int d = 1; d < 64; d <<= 1){
    int y = __shfl_up(x, d);
    if (lane >= d) x += y;
  }
  if (lane == 63) wsum[wv] = x;
  __syncthreads();
  int wpre = 0, tot = 0;
  #pragma unroll
  for (int w2 = 0; w2 < 16; w2++){
    int s = wsum[w2];
    if (w2 < wv) wpre += s;
    tot += s;
  }
  int tbase = wpre + (x - tsum);          // exclusive thread base (local)
  #pragma unroll
  for (int j = 0; j < 8; j++){
    int i = i0 + j;
    if (i < n) off[i] = tbase + loc[j];
  }
  if (t == 0) part[b] = tot;
}

// Pass 2: add segment-local prefix of tile totals; write array totals.
__global__ __launch_bounds__(1024) void k_scan_add(
    int* __restrict__ off_u, int* __restrict__ off_i,
    const int* __restrict__ part)
{
  __shared__ int sp[NBT];
  const int b = blockIdx.x;
  const int t = threadIdx.x;
  if (t < NBT) sp[t] = part[t];
  __syncthreads();

  int* off; int n, base, segbeg;
  if (b < NBU){ off = off_u; n = NUSR; base = b*8192; segbeg = 0; }
  else        { off = off_i; n = NENT; base = (b-NBU)*8192; segbeg = NBU; }

  int pre = 0;
  for (int j = segbeg; j < b; j++) pre += sp[j];

  if (pre != 0){
    const int i0 = base + t*8;
    #pragma unroll
    for (int j = 0; j < 8; j++){
      int i = i0 + j;
      if (i < n) off[i] += pre;
    }
  }
  if (b == 0 && t == 0){
    int tu = 0; for (int j = 0; j < NBU; j++) tu += sp[j];
    int ti = 0; for (int j = NBU; j < NBT; j++) ti += sp[j];
    off_u[NUSR] = tu;
    off_i[NENT] = ti;
  }
}

__global__ __launch_bounds__(256) void k_scatter(
    const int* __restrict__ ui, const int* __restrict__ ii,
    const int* __restrict__ off_u, const int* __restrict__ off_i,
    int* __restrict__ cur_u, int* __restrict__ cur_i,
    int2* __restrict__ pair_u, int2* __restrict__ pair_i)
{
  int e = blockIdx.x*256 + threadIdx.x;
  if (e >= NEDGE) return;
  int u = ui[e], it = ii[e];
  int p = atomicAdd(&cur_u[u],  1); pair_u[off_u[u]  + p] = make_int2(u, it);
  int q = atomicAdd(&cur_i[it], 1); pair_i[off_i[it] + q] = make_int2(u, it);
}

// ---------------------------------------------------------------------------
// Per-slot 128->64 matvec via MFMA with 3-way bf16 truncation split (exact
// mantissa tiling; dropped terms ~2^-24 rel, same order as f32 rounding).
// Processes CSR SLOTS: row indices come from pair[slot], outputs rel[slot]
// (fp16: only consumed in sim-dot products; ~2^-11 relative, well inside
// the absmax budget) and rtype[slot] (argmax from f32 accs) contiguous.
// Block: 512 threads = 8 waves, 128 slots (16/wave).
// ---------------------------------------------------------------------------
template<int WITH_ARGMAX, int SWAP>
__global__ __launch_bounds__(512,4) void k_matvec(
    const float* __restrict__ rowsA, const float* __restrict__ rowsB,
    const int2* __restrict__ pair,
    const float* __restrict__ lat,
    const float* __restrict__ Ww, const float* __restrict__ Wb,
    f16* __restrict__ rel, int* __restrict__ rtype)
{
  // W planes: hi @0, mid @16384, lo @32768 (each 64 rows x 256B, swizzled).
  // After the post-K-loop barrier this region is reused as the per-wave
  // transpose buffer (8 waves x 16 x 68 f32 = 34816B <= 49152B).
  __shared__ __align__(16) char smem[49152];
  __shared__ float lat_lds[192];

  const int t  = threadIdx.x;
  const int e0 = blockIdx.x * 128;

  // ---- stage W (f32 [64][128]) as 3 swizzled bf16 planes: byte ^= (row&7)<<4
  {
    const int n  = t >> 3;              // W row (out dim)
    const int kb = (t & 7) * 16;        // f32 elem base within row
    const float4* s4 = (const float4*)(Ww + n*128 + kb);
    float4 q0 = s4[0], q1 = s4[1], q2 = s4[2], q3 = s4[3];
    float xs[16] = {q0.x,q0.y,q0.z,q0.w, q1.x,q1.y,q1.z,q1.w,
                    q2.x,q2.y,q2.z,q2.w, q3.x,q3.y,q3.z,q3.w};
    unsigned uh[8], um[8], ul[8];
    #pragma unroll
    for (int p = 0; p < 8; p++){
      float a = xs[2*p], b = xs[2*p+1];
      unsigned ua = __float_as_uint(a), ub = __float_as_uint(b);
      uh[p] = (ua >> 16) | (ub & 0xffff0000u);
      float ra = a - __uint_as_float(ua & 0xffff0000u);
      float rb = b - __uint_as_float(ub & 0xffff0000u);
      unsigned va = __float_as_uint(ra), vb = __float_as_uint(rb);
      um[p] = (va >> 16) | (vb & 0xffff0000u);
      float sa = ra - __uint_as_float(va & 0xffff0000u);
      float sb = rb - __uint_as_float(vb & 0xffff0000u);
      ul[p] = (__float_as_uint(sa) >> 16) | (__float_as_uint(sb) & 0xffff0000u);
    }
    char* dh = smem + n*256;
    const unsigned sw = (unsigned)((n & 7) << 4);
    const unsigned b0 = ((unsigned)(kb*2))      ^ sw;
    const unsigned b1 = ((unsigned)(kb*2 + 16)) ^ sw;
    *(uint4*)(dh + b0)         = make_uint4(uh[0],uh[1],uh[2],uh[3]);
    *(uint4*)(dh + b1)         = make_uint4(uh[4],uh[5],uh[6],uh[7]);
    *(uint4*)(dh + 16384 + b0) = make_uint4(um[0],um[1],um[2],um[3]);
    *(uint4*)(dh + 16384 + b1) = make_uint4(um[4],um[5],um[6],um[7]);
    *(uint4*)(dh + 32768 + b0) = make_uint4(ul[0],ul[1],ul[2],ul[3]);
    *(uint4*)(dh + 32768 + b1) = make_uint4(ul[4],ul[5],ul[6],ul[7]);
  }
  if (WITH_ARGMAX && t < 192) lat_lds[t] = lat[t];
  __syncthreads();

  const int w = t >> 6, l = t & 63;
  const int g = l >> 4, c = l & 15;

  const int sl = min(e0 + w*16 + c, NEDGE-1);
  const int2 pr = pair[sl];
  const int ia = SWAP ? pr.y : pr.x;
  const int ib = SWAP ? pr.x : pr.y;
  const float* pa = rowsA + (size_t)ia*64 + g*8;
  const float* pb = rowsB + (size_t)ib*64 + g*8;

  f32x4 acc[4];
  #pragma unroll
  for (int nt = 0; nt < 4; nt++){
    float bv = Wb[nt*16 + c];           // bias folded into C-init
    f32x4 a = {bv, bv, bv, bv};
    acc[nt] = a;
  }

  const unsigned sw = (unsigned)((c & 7) << 4);
  #pragma unroll
  for (int kk = 0; kk < 4; kk++){       // K=128 in 4 MFMA steps of 32
    const float* src = (kk < 2) ? (pa + (kk & 1)*32) : (pb + (kk & 1)*32);
    float4 x0 = *(const float4*)src;
    float4 x1 = *(const float4*)(src + 4);
    // 3-way truncation split
    float xsv[8] = {x0.x,x0.y,x0.z,x0.w, x1.x,x1.y,x1.z,x1.w};
    union { unsigned u[4]; bf16x8 v; } H, M, L;
    #pragma unroll
    for (int p = 0; p < 4; p++){
      float a = xsv[2*p], b = xsv[2*p+1];
      unsigned ua = __float_as_uint(a), ub = __float_as_uint(b);
      H.u[p] = (ua >> 16) | (ub & 0xffff0000u);
      float ra = a - __uint_as_float(ua & 0xffff0000u);
      float rb = b - __uint_as_float(ub & 0xffff0000u);
      unsigned va = __float_as_uint(ra), vb = __float_as_uint(rb);
      M.u[p] = (va >> 16) | (vb & 0xffff0000u);
      float sa = ra - __uint_as_float(va & 0xffff0000u);
      float sb = rb - __uint_as_float(vb & 0xffff0000u);
      L.u[p] = (__float_as_uint(sa) >> 16) | (__float_as_uint(sb) & 0xffff0000u);
    }
    bf16x8 a0 = H.v, a1 = M.v, a2 = L.v;
    const unsigned xoff = ((unsigned)(kk*64 + g*16)) ^ sw;
    #pragma unroll
    for (int nt = 0; nt < 4; nt++){
      const char* base = smem + (unsigned)((nt*16 + c)*256) + xoff;
      bf16x8 b0 = *(const bf16x8*)base;
      bf16x8 b1 = *(const bf16x8*)(base + 16384);
      bf16x8 b2 = *(const bf16x8*)(base + 32768);
      // smallest-magnitude terms first for accumulation
      acc[nt] = __builtin_amdgcn_mfma_f32_16x16x32_bf16(a0, b2, acc[nt], 0, 0, 0);
      acc[nt] = __builtin_amdgcn_mfma_f32_16x16x32_bf16(a1, b1, acc[nt], 0, 0, 0);
      acc[nt] = __builtin_amdgcn_mfma_f32_16x16x32_bf16(a2, b0, acc[nt], 0, 0, 0);
      acc[nt] = __builtin_amdgcn_mfma_f32_16x16x32_bf16(a0, b1, acc[nt], 0, 0, 0);
      acc[nt] = __builtin_amdgcn_mfma_f32_16x16x32_bf16(a1, b0, acc[nt], 0, 0, 0);
      acc[nt] = __builtin_amdgcn_mfma_f32_16x16x32_bf16(a0, b0, acc[nt], 0, 0, 0);
    }
  }

  // leaky_relu(0.01)
  #pragma unroll
  for (int nt = 0; nt < 4; nt++)
    #pragma unroll
    for (int r = 0; r < 4; r++){
      float v = acc[nt][r];
      acc[nt][r] = v > 0.f ? v : 0.01f*v;
    }

  // argmax over latent scores, straight from f32 accumulators
  if (WITH_ARGMAX){
    int rt[4];
    #pragma unroll
    for (int r = 0; r < 4; r++){
      float s0 = 0.f, s1 = 0.f, s2 = 0.f;
      #pragma unroll
      for (int nt = 0; nt < 4; nt++){
        float a = acc[nt][r];
        s0 += a * lat_lds[      nt*16 + c];
        s1 += a * lat_lds[ 64 + nt*16 + c];
        s2 += a * lat_lds[128 + nt*16 + c];
      }
      #pragma unroll
      for (int m = 1; m < 16; m <<= 1){   // reduce across out-dims (lane&15)
        s0 += __shfl_xor(s0, m);
        s1 += __shfl_xor(s1, m);
        s2 += __shfl_xor(s2, m);
      }
      int bf = 0; float bs = s0;
      if (s1 > bs){ bs = s1; bf = 1; }   // strict > : first-max like jnp.argmax
      if (s2 > bs){ bs = s2; bf = 2; }
      rt[r] = bf;
    }
    if (c == 0){
      int eb = e0 + w*16 + g*4;
      if (eb < NEDGE)
        *(int4*)(rtype + eb) = make_int4(rt[0], rt[1], rt[2], rt[3]);
    }
  }

  // All waves have finished reading the W planes after this barrier;
  // smem is then reused as the per-wave transpose buffer.
  __syncthreads();
  float* tb = (float*)smem + w*1088;    // [16][68] f32, 16B-aligned rows
  #pragma unroll
  for (int nt = 0; nt < 4; nt++)
    #pragma unroll
    for (int r = 0; r < 4; r++)
      tb[(g*4 + r)*68 + nt*16 + c] = acc[nt][r];

  // fp16 coalesced stores: lanes 0-7 cover one edge's 128B row
  #pragma unroll
  for (int r = 0; r < 2; r++){
    int g2 = l + 64*r;
    int el = g2 >> 3, d0 = (g2 & 7) << 3;
    int er = e0 + w*16 + el;
    if (er < NEDGE){
      float4 q0 = *(const float4*)&tb[el*68 + d0];
      float4 q1 = *(const float4*)&tb[el*68 + d0 + 4];
      f16x8 h = {(f16)q0.x,(f16)q0.y,(f16)q0.z,(f16)q0.w,
                 (f16)q1.x,(f16)q1.y,(f16)q1.z,(f16)q1.w};
      *(f16x8*)(rel + (size_t)er*64 + d0) = h;
    }
  }
}

// ---------------------------------------------------------------------------
// User side: ONE 16-LANE GROUP PER USER (4 users/wave, 16 users/block).
// Lane c = dim-slice (f32x4). Pass-1 sums are group-local (zero shuffles);
// only the per-edge dot and the epilogue n2 need 4-step 16-lane reduces.
// All per-slot streams (pair, rtype, rel) are CSR-contiguous.
// ---------------------------------------------------------------------------
__global__ __launch_bounds__(256) void k_user(
    const float* __restrict__ ent, const float* __restrict__ usr,
    const float* __restrict__ w3,
    const int2* __restrict__ pair_u, const int* __restrict__ rtype,
    const f16* __restrict__ rel,
    const int* __restrict__ off_u, float* __restrict__ out_user)
{
  const int t = threadIdx.x;
  const int c = t & 15;
  const int u = blockIdx.x*16 + (t >> 4);
  if (u >= NUSR) return;
  const int beg = off_u[u], end = off_u[u+1];

  const f32x4 z = {0.f,0.f,0.f,0.f};
  f32x4 s0 = z, s1 = z, s2 = z;
  int c0 = 0, c1 = 0, c2 = 0;
  for (int k = beg; k < end; k++){
    int item = pair_u[k].y;
    int f = rtype[k];
    f32x4 ip = *(const f32x4*)(ent + (size_t)item*64 + (c<<2));
    if (f == 0){ s0 += ip; c0++; }
    else if (f == 1){ s1 += ip; c1++; }
    else { s2 += ip; c2++; }
  }
  const float d0 = fmaxf((float)c0, 1.f);
  const float d1 = fmaxf((float)c1, 1.f);
  const float d2 = fmaxf((float)c2, 1.f);

  f32x4 a0 = z, a1 = z, a2 = z;
  for (int k = beg; k < end; k++){
    int item = pair_u[k].y;
    int f = rtype[k];
    f32x4 ip = *(const f32x4*)(ent + (size_t)item*64 + (c<<2));
    f16x4 hv = *(const f16x4*)(rel + (size_t)k*64 + (c<<2));
    f32x4 rv = {(float)hv[0], (float)hv[1], (float)hv[2], (float)hv[3]};
    f32x4 sf = (f == 0) ? s0 : ((f == 1) ? s1 : s2);
    float dd = (f == 0) ? d0 : ((f == 1) ? d1 : d2);
    float p = rv[0]*sf[0] + rv[1]*sf[1] + rv[2]*sf[2] + rv[3]*sf[3];
    #pragma unroll
    for (int m = 1; m < 16; m <<= 1) p += __shfl_xor(p, m);
    float sim = p / dd;                 // dot(rel, u_) with mean folded in
    f32x4 tv = ip * sim;
    if (f == 0) a0 += tv; else if (f == 1) a1 += tv; else a2 += tv;
  }

  float wa = w3[0], wb = w3[1], wc = w3[2];
  float mx = fmaxf(wa, fmaxf(wb, wc));
  float ea = expf(wa-mx), eb = expf(wb-mx), ec = expf(wc-mx);
  float inv = 1.f/(ea+eb+ec);
  f32x4 ue = *(const f32x4*)(usr + (size_t)u*64 + (c<<2));
  f32x4 av[3] = {a0, a1, a2};
  float dv[3] = {d0, d1, d2}, wv[3] = {ea*inv, eb*inv, ec*inv};
  f32x4 o = z;
  #pragma unroll
  for (int f = 0; f < 3; f++){
    f32x4 v = av[f] / dv[f];
    float n2 = v[0]*v[0] + v[1]*v[1] + v[2]*v[2] + v[3]*v[3];
    #pragma unroll
    for (int m = 1; m < 16; m <<= 1) n2 += __shfl_xor(n2, m);
    float n = sqrtf(n2);
    float fac = (n2/(n2 + 1.f)) / fmaxf(n, 1e-12f);
    o += (v * fac + ue) * wv[f];
  }
  *(f32x4*)(out_user + (size_t)u*64 + (c<<2)) = o;
}

// ---------------------------------------------------------------------------
// Entity side: one 16-lane group per entity (4/wave, 16/block).
// ---------------------------------------------------------------------------
__global__ __launch_bounds__(256) void k_ent(
    const float* __restrict__ ent, const float* __restrict__ usr,
    const int2* __restrict__ pair_i, const f16* __restrict__ rel,
    const int* __restrict__ off_i, float* __restrict__ out_ent)
{
  const int t = threadIdx.x;
  const int c = t & 15;
  const int i = blockIdx.x*16 + (t >> 4);
  if (i >= NENT) return;
  const int beg = off_i[i], end = off_i[i+1];

  const f32x4 z = {0.f,0.f,0.f,0.f};
  f32x4 s = z;
  for (int k = beg; k < end; k++){
    int us = pair_i[k].x;
    s += *(const f32x4*)(usr + (size_t)us*64 + (c<<2));
  }
  const float d = fmaxf((float)(end - beg), 1.f);

  f32x4 a = z;
  for (int k = beg; k < end; k++){
    int us = pair_i[k].x;
    f32x4 up = *(const f32x4*)(usr + (size_t)us*64 + (c<<2));
    f16x4 hv = *(const f16x4*)(rel + (size_t)k*64 + (c<<2));
    f32x4 rv = {(float)hv[0], (float)hv[1], (float)hv[2], (float)hv[3]};
    float p = rv[0]*s[0] + rv[1]*s[1] + rv[2]*s[2] + rv[3]*s[3];
    #pragma unroll
    for (int m = 1; m < 16; m <<= 1) p += __shfl_xor(p, m);
    a += up * (p / d);
  }

  f32x4 v = a / d;
  float n2 = v[0]*v[0] + v[1]*v[1] + v[2]*v[2] + v[3]*v[3];
  #pragma unroll
  for (int m = 1; m < 16; m <<= 1) n2 += __shfl_xor(n2, m);
  float n = sqrtf(n2);
  float fac = (n2/(n2 + 1.f)) / fmaxf(n, 1e-12f);
  f32x4 ev = *(const f32x4*)(ent + (size_t)i*64 + (c<<2));
  *(f32x4*)(out_ent + (size_t)i*64 + (c<<2)) = v * fac + ev;
}

// ---------------------------------------------------------------------------
// Workspace layout (f32 element offsets). rel is now fp16 (64 MB in a 128 MB
// slot, offsets unchanged). Live set rel(64)+ent(51)+usr(26) = 141 MB << L3.
//   rel     f16 [E*64]   @ 0            (64 MB used)
//   zero-block           @ 32,000,000:  deg_u(100k) cur_u(100k) deg_i(200k) cur_i(200k)
//   off_u   [U+1]        @ 32,600,000
//   off_i   [ENT+1]      @ 32,700,004
//   pair_u  int2 [E]     @ 32,900,008   (byte offset %8 == 0)
//   pair_i  int2 [E]     @ 33,900,008
//   rtype   [E]          @ 34,900,008
//   part    [NBT]        @ 35,400,008
// ---------------------------------------------------------------------------
extern "C" void kernel_launch(void* const* d_in, const int* in_sizes, int n_in,
                              void* d_out, int out_size, void* d_ws, size_t ws_size,
                              hipStream_t stream) {
  const float* ent = (const float*)d_in[0];
  const float* usr = (const float*)d_in[1];
  const float* lat = (const float*)d_in[2];
  const int*   ui  = (const int*)d_in[3];
  const int*   ii  = (const int*)d_in[4];
  const float* Ww  = (const float*)d_in[5];
  const float* Wb  = (const float*)d_in[6];
  const float* Wiw = (const float*)d_in[7];
  const float* Wib = (const float*)d_in[8];
  const float* w3  = (const float*)d_in[9];

  float* ws = (float*)d_ws;
  f16*   rel    = (f16*)ws;
  int*   deg_u  = (int*)(ws + 32000000ull);
  int*   cur_u  = deg_u + 100000;
  int*   deg_i  = cur_u + 100000;
  int*   cur_i  = deg_i + 200000;
  int*   off_u  = (int*)(ws + 32600000ull);
  int*   off_i  = (int*)(ws + 32700004ull);
  int2*  pair_u = (int2*)(ws + 32900008ull);
  int2*  pair_i = (int2*)(ws + 33900008ull);
  int*   rtype  = (int*)(ws + 34900008ull);
  int*   part   = (int*)(ws + 35400008ull);

  float* out_ent  = (float*)d_out;
  float* out_user = (float*)d_out + (size_t)NENT*64;

  hipMemsetAsync(deg_u, 0, 600000*sizeof(int), stream);   // deg+cur, both sides

  k_hist<<<1954, 256, 0, stream>>>(ui, ii, deg_u, deg_i);
  k_scan_part<<<NBT, 1024, 0, stream>>>(deg_u, off_u, deg_i, off_i, part);
  k_scan_add<<<NBT, 1024, 0, stream>>>(off_u, off_i, part);
  k_scatter<<<1954, 256, 0, stream>>>(ui, ii, off_u, off_i,
                                      cur_u, cur_i, pair_u, pair_i);

  // relation_ui = leaky(concat([user, item]) @ Ww^T + b), + argmax -> rtype
  k_matvec<1,0><<<3907, 512, 0, stream>>>(usr, ent, pair_u, lat, Ww, Wb,
                                          rel, rtype);
  k_user<<<6250, 256, 0, stream>>>(ent, usr, w3, pair_u, rtype, rel,
                                   off_u, out_user);
  // relation_iu = leaky(concat([item, user]) @ Wiw^T + b)  (reuses rel buffer)
  k_matvec<0,1><<<3907, 512, 0, stream>>>(ent, usr, pair_i, lat, Wiw, Wib,
                                          rel, rtype);
  k_ent<<<12500, 256, 0, stream>>>(ent, usr, pair_i, rel,
                                   off_i, out_ent);
}

// Round 7
// 486.411 us; speedup vs baseline: 2.4772x; 1.0297x over previous
//
#include <hip/hip_runtime.h>
#include <stdint.h>

#define NEDGE 500000
#define NUSR  100000
#define NENT  200000

// scan tiling: 8192 elems/block; 13 blocks cover NUSR, 25 cover NENT
#define NBU 13
#define NBI 25
#define NBT 38

typedef __attribute__((ext_vector_type(8))) short bf16x8;
typedef __attribute__((ext_vector_type(4))) float f32x4;
typedef _Float16 f16;
typedef __attribute__((ext_vector_type(4))) _Float16 f16x4;
typedef __attribute__((ext_vector_type(8))) _Float16 f16x8;

// ---------------------------------------------------------------------------
// CSR build: histogram -> two-pass parallel scan -> cursor scatter.
// ---------------------------------------------------------------------------
__global__ __launch_bounds__(256) void k_hist(
    const int* __restrict__ ui, const int* __restrict__ ii,
    int* __restrict__ deg_u, int* __restrict__ deg_i)
{
  int e = blockIdx.x*256 + threadIdx.x;
  if (e >= NEDGE) return;
  atomicAdd(&deg_u[ui[e]], 1);
  atomicAdd(&deg_i[ii[e]], 1);
}

// Pass 1: per-block local exclusive scan of an 8192-elem tile + tile total.
__global__ __launch_bounds__(1024) void k_scan_part(
    const int* __restrict__ deg_u, int* __restrict__ off_u,
    const int* __restrict__ deg_i, int* __restrict__ off_i,
    int* __restrict__ part)
{
  __shared__ int wsum[16];
  const int b = blockIdx.x;
  const int t = threadIdx.x, lane = t & 63, wv = t >> 6;

  const int* deg; int* off; int n, base;
  if (b < NBU){ deg = deg_u; off = off_u; n = NUSR; base = b*8192; }
  else        { deg = deg_i; off = off_i; n = NENT; base = (b-NBU)*8192; }

  int loc[8]; int tsum = 0;
  const int i0 = base + t*8;
  #pragma unroll
  for (int j = 0; j < 8; j++){
    int i = i0 + j; int v = (i < n) ? deg[i] : 0;
    loc[j] = tsum; tsum += v;
  }
  int x = tsum;                           // inclusive wave scan
  #pragma unroll
  for (int d = 1; d < 64; d <<= 1){
    int y = __shfl_up(x, d);
    if (lane >= d) x += y;
  }
  if (lane == 63) wsum[wv] = x;
  __syncthreads();
  int wpre = 0, tot = 0;
  #pragma unroll
  for (int w2 = 0; w2 < 16; w2++){
    int s = wsum[w2];
    if (w2 < wv) wpre += s;
    tot += s;
  }
  int tbase = wpre + (x - tsum);          // exclusive thread base (local)
  #pragma unroll
  for (int j = 0; j < 8; j++){
    int i = i0 + j;
    if (i < n) off[i] = tbase + loc[j];
  }
  if (t == 0) part[b] = tot;
}

// Pass 2: add segment-local prefix of tile totals; write array totals.
__global__ __launch_bounds__(1024) void k_scan_add(
    int* __restrict__ off_u, int* __restrict__ off_i,
    const int* __restrict__ part)
{
  __shared__ int sp[NBT];
  const int b = blockIdx.x;
  const int t = threadIdx.x;
  if (t < NBT) sp[t] = part[t];
  __syncthreads();

  int* off; int n, base, segbeg;
  if (b < NBU){ off = off_u; n = NUSR; base = b*8192; segbeg = 0; }
  else        { off = off_i; n = NENT; base = (b-NBU)*8192; segbeg = NBU; }

  int pre = 0;
  for (int j = segbeg; j < b; j++) pre += sp[j];

  if (pre != 0){
    const int i0 = base + t*8;
    #pragma unroll
    for (int j = 0; j < 8; j++){
      int i = i0 + j;
      if (i < n) off[i] += pre;
    }
  }
  if (b == 0 && t == 0){
    int tu = 0; for (int j = 0; j < NBU; j++) tu += sp[j];
    int ti = 0; for (int j = NBU; j < NBT; j++) ti += sp[j];
    off_u[NUSR] = tu;
    off_i[NENT] = ti;
  }
}

__global__ __launch_bounds__(256) void k_scatter(
    const int* __restrict__ ui, const int* __restrict__ ii,
    const int* __restrict__ off_u, const int* __restrict__ off_i,
    int* __restrict__ cur_u, int* __restrict__ cur_i,
    int2* __restrict__ pair_u, int2* __restrict__ pair_i)
{
  int e = blockIdx.x*256 + threadIdx.x;
  if (e >= NEDGE) return;
  int u = ui[e], it = ii[e];
  int p = atomicAdd(&cur_u[u],  1); pair_u[off_u[u]  + p] = make_int2(u, it);
  int q = atomicAdd(&cur_i[it], 1); pair_i[off_i[it] + q] = make_int2(u, it);
}

// ---------------------------------------------------------------------------
// Per-slot 128->64 matvec via MFMA with 3-way bf16 truncation split.
// R7: each wave owns TWO 16-slot tiles (32 slots); B-fragments (W planes from
// LDS) are read ONCE per (kk,nt) and feed both tiles' MFMAs -> LDS W-read
// traffic and staging cost per edge halve. Block = 512 thr / 256 slots.
// ---------------------------------------------------------------------------
template<int WITH_ARGMAX, int SWAP>
__global__ __launch_bounds__(512,4) void k_matvec(
    const float* __restrict__ rowsA, const float* __restrict__ rowsB,
    const int2* __restrict__ pair,
    const float* __restrict__ lat,
    const float* __restrict__ Ww, const float* __restrict__ Wb,
    f16* __restrict__ rel, int* __restrict__ rtype)
{
  // W planes: hi @0, mid @16384, lo @32768 (each 64 rows x 256B, swizzled).
  // After the post-K-loop barrier, the first 34.8KB are reused as per-wave
  // transpose buffers (8 waves x 16 x 68 f32), tile-sequentially.
  __shared__ __align__(16) char smem[49152];
  __shared__ float lat_lds[192];

  const int t  = threadIdx.x;
  const int e0 = blockIdx.x * 256;

  // ---- stage W (f32 [64][128]) as 3 swizzled bf16 planes: byte ^= (row&7)<<4
  {
    const int n  = t >> 3;              // W row (out dim)
    const int kb = (t & 7) * 16;        // f32 elem base within row
    const float4* s4 = (const float4*)(Ww + n*128 + kb);
    float4 q0 = s4[0], q1 = s4[1], q2 = s4[2], q3 = s4[3];
    float xs[16] = {q0.x,q0.y,q0.z,q0.w, q1.x,q1.y,q1.z,q1.w,
                    q2.x,q2.y,q2.z,q2.w, q3.x,q3.y,q3.z,q3.w};
    unsigned uh[8], um[8], ul[8];
    #pragma unroll
    for (int p = 0; p < 8; p++){
      float a = xs[2*p], b = xs[2*p+1];
      unsigned ua = __float_as_uint(a), ub = __float_as_uint(b);
      uh[p] = (ua >> 16) | (ub & 0xffff0000u);
      float ra = a - __uint_as_float(ua & 0xffff0000u);
      float rb = b - __uint_as_float(ub & 0xffff0000u);
      unsigned va = __float_as_uint(ra), vb = __float_as_uint(rb);
      um[p] = (va >> 16) | (vb & 0xffff0000u);
      float sa = ra - __uint_as_float(va & 0xffff0000u);
      float sb = rb - __uint_as_float(vb & 0xffff0000u);
      ul[p] = (__float_as_uint(sa) >> 16) | (__float_as_uint(sb) & 0xffff0000u);
    }
    char* dh = smem + n*256;
    const unsigned sw = (unsigned)((n & 7) << 4);
    const unsigned b0 = ((unsigned)(kb*2))      ^ sw;
    const unsigned b1 = ((unsigned)(kb*2 + 16)) ^ sw;
    *(uint4*)(dh + b0)         = make_uint4(uh[0],uh[1],uh[2],uh[3]);
    *(uint4*)(dh + b1)         = make_uint4(uh[4],uh[5],uh[6],uh[7]);
    *(uint4*)(dh + 16384 + b0) = make_uint4(um[0],um[1],um[2],um[3]);
    *(uint4*)(dh + 16384 + b1) = make_uint4(um[4],um[5],um[6],um[7]);
    *(uint4*)(dh + 32768 + b0) = make_uint4(ul[0],ul[1],ul[2],ul[3]);
    *(uint4*)(dh + 32768 + b1) = make_uint4(ul[4],ul[5],ul[6],ul[7]);
  }
  if (WITH_ARGMAX && t < 192) lat_lds[t] = lat[t];
  __syncthreads();

  const int w = t >> 6, l = t & 63;
  const int g = l >> 4, c = l & 15;

  const int sl0 = min(e0 + w*32 + c,      NEDGE-1);
  const int sl1 = min(e0 + w*32 + 16 + c, NEDGE-1);
  const int2 pr0 = pair[sl0];
  const int2 pr1 = pair[sl1];
  const int ia0 = SWAP ? pr0.y : pr0.x, ib0 = SWAP ? pr0.x : pr0.y;
  const int ia1 = SWAP ? pr1.y : pr1.x, ib1 = SWAP ? pr1.x : pr1.y;
  const float* pa0 = rowsA + (size_t)ia0*64 + g*8;
  const float* pb0 = rowsB + (size_t)ib0*64 + g*8;
  const float* pa1 = rowsA + (size_t)ia1*64 + g*8;
  const float* pb1 = rowsB + (size_t)ib1*64 + g*8;

  f32x4 acc0[4], acc1[4];
  #pragma unroll
  for (int nt = 0; nt < 4; nt++){
    float bv = Wb[nt*16 + c];           // bias folded into C-init
    f32x4 a = {bv, bv, bv, bv};
    acc0[nt] = a; acc1[nt] = a;
  }

  const unsigned sw = (unsigned)((c & 7) << 4);
  #pragma unroll
  for (int kk = 0; kk < 4; kk++){       // K=128 in 4 MFMA steps of 32
    const float* s0 = (kk < 2) ? (pa0 + (kk & 1)*32) : (pb0 + (kk & 1)*32);
    const float* s1 = (kk < 2) ? (pa1 + (kk & 1)*32) : (pb1 + (kk & 1)*32);
    float4 x00 = *(const float4*)s0;
    float4 x01 = *(const float4*)(s0 + 4);
    float4 x10 = *(const float4*)s1;
    float4 x11 = *(const float4*)(s1 + 4);
    // 3-way truncation split, both tiles
    bf16x8 a00, a01, a02, a10, a11, a12;
    {
      float xsv[16] = {x00.x,x00.y,x00.z,x00.w, x01.x,x01.y,x01.z,x01.w,
                       x10.x,x10.y,x10.z,x10.w, x11.x,x11.y,x11.z,x11.w};
      union { unsigned u[8]; struct { bf16x8 v0, v1; }; } H, M, L;
      #pragma unroll
      for (int p = 0; p < 8; p++){
        float a = xsv[2*p], b = xsv[2*p+1];
        unsigned ua = __float_as_uint(a), ub = __float_as_uint(b);
        H.u[p] = (ua >> 16) | (ub & 0xffff0000u);
        float ra = a - __uint_as_float(ua & 0xffff0000u);
        float rb = b - __uint_as_float(ub & 0xffff0000u);
        unsigned va = __float_as_uint(ra), vb = __float_as_uint(rb);
        M.u[p] = (va >> 16) | (vb & 0xffff0000u);
        float sa = ra - __uint_as_float(va & 0xffff0000u);
        float sb = rb - __uint_as_float(vb & 0xffff0000u);
        L.u[p] = (__float_as_uint(sa) >> 16) | (__float_as_uint(sb) & 0xffff0000u);
      }
      a00 = H.v0; a01 = M.v0; a02 = L.v0;
      a10 = H.v1; a11 = M.v1; a12 = L.v1;
    }
    const unsigned xoff = ((unsigned)(kk*64 + g*16)) ^ sw;
    #pragma unroll
    for (int nt = 0; nt < 4; nt++){
      const char* base = smem + (unsigned)((nt*16 + c)*256) + xoff;
      bf16x8 b0 = *(const bf16x8*)base;
      bf16x8 b1 = *(const bf16x8*)(base + 16384);
      bf16x8 b2 = *(const bf16x8*)(base + 32768);
      // smallest-magnitude terms first; B-frags shared by both tiles
      acc0[nt] = __builtin_amdgcn_mfma_f32_16x16x32_bf16(a00, b2, acc0[nt], 0, 0, 0);
      acc1[nt] = __builtin_amdgcn_mfma_f32_16x16x32_bf16(a10, b2, acc1[nt], 0, 0, 0);
      acc0[nt] = __builtin_amdgcn_mfma_f32_16x16x32_bf16(a01, b1, acc0[nt], 0, 0, 0);
      acc1[nt] = __builtin_amdgcn_mfma_f32_16x16x32_bf16(a11, b1, acc1[nt], 0, 0, 0);
      acc0[nt] = __builtin_amdgcn_mfma_f32_16x16x32_bf16(a02, b0, acc0[nt], 0, 0, 0);
      acc1[nt] = __builtin_amdgcn_mfma_f32_16x16x32_bf16(a12, b0, acc1[nt], 0, 0, 0);
      acc0[nt] = __builtin_amdgcn_mfma_f32_16x16x32_bf16(a00, b1, acc0[nt], 0, 0, 0);
      acc1[nt] = __builtin_amdgcn_mfma_f32_16x16x32_bf16(a10, b1, acc1[nt], 0, 0, 0);
      acc0[nt] = __builtin_amdgcn_mfma_f32_16x16x32_bf16(a01, b0, acc0[nt], 0, 0, 0);
      acc1[nt] = __builtin_amdgcn_mfma_f32_16x16x32_bf16(a11, b0, acc1[nt], 0, 0, 0);
      acc0[nt] = __builtin_amdgcn_mfma_f32_16x16x32_bf16(a00, b0, acc0[nt], 0, 0, 0);
      acc1[nt] = __builtin_amdgcn_mfma_f32_16x16x32_bf16(a10, b0, acc1[nt], 0, 0, 0);
    }
  }

  // leaky_relu(0.01), both tiles
  #pragma unroll
  for (int nt = 0; nt < 4; nt++)
    #pragma unroll
    for (int r = 0; r < 4; r++){
      float v0 = acc0[nt][r];
      acc0[nt][r] = v0 > 0.f ? v0 : 0.01f*v0;
      float v1 = acc1[nt][r];
      acc1[nt][r] = v1 > 0.f ? v1 : 0.01f*v1;
    }

  // argmax over latent scores, straight from f32 accumulators (both tiles)
  if (WITH_ARGMAX){
    int rt0[4], rt1[4];
    #pragma unroll
    for (int r = 0; r < 4; r++){
      float s00=0.f, s01=0.f, s02=0.f, s10=0.f, s11=0.f, s12=0.f;
      #pragma unroll
      for (int nt = 0; nt < 4; nt++){
        float a0 = acc0[nt][r], a1 = acc1[nt][r];
        float l0 = lat_lds[      nt*16 + c];
        float l1 = lat_lds[ 64 + nt*16 + c];
        float l2 = lat_lds[128 + nt*16 + c];
        s00 += a0*l0; s01 += a0*l1; s02 += a0*l2;
        s10 += a1*l0; s11 += a1*l1; s12 += a1*l2;
      }
      #pragma unroll
      for (int m = 1; m < 16; m <<= 1){   // reduce across out-dims (lane&15)
        s00 += __shfl_xor(s00, m); s01 += __shfl_xor(s01, m); s02 += __shfl_xor(s02, m);
        s10 += __shfl_xor(s10, m); s11 += __shfl_xor(s11, m); s12 += __shfl_xor(s12, m);
      }
      int b0i = 0; float bs0 = s00;
      if (s01 > bs0){ bs0 = s01; b0i = 1; }
      if (s02 > bs0){ bs0 = s02; b0i = 2; }
      rt0[r] = b0i;
      int b1i = 0; float bs1 = s10;
      if (s11 > bs1){ bs1 = s11; b1i = 1; }
      if (s12 > bs1){ bs1 = s12; b1i = 2; }
      rt1[r] = b1i;
    }
    if (c == 0){
      int eb0 = e0 + w*32 + g*4;
      if (eb0 < NEDGE)
        *(int4*)(rtype + eb0) = make_int4(rt0[0], rt0[1], rt0[2], rt0[3]);
      int eb1 = e0 + w*32 + 16 + g*4;
      if (eb1 < NEDGE)
        *(int4*)(rtype + eb1) = make_int4(rt1[0], rt1[1], rt1[2], rt1[3]);
    }
  }

  // All waves have finished reading the W planes after this barrier;
  // per-wave tb region (within W planes) is reused tile-sequentially.
  __syncthreads();
  float* tb = (float*)smem + w*1088;    // [16][68] f32, 16B-aligned rows
  #pragma unroll
  for (int et = 0; et < 2; et++){
    #pragma unroll
    for (int nt = 0; nt < 4; nt++)
      #pragma unroll
      for (int r = 0; r < 4; r++)
        tb[(g*4 + r)*68 + nt*16 + c] = et ? acc1[nt][r] : acc0[nt][r];

    // fp16 coalesced stores: lanes 0-7 cover one edge's 128B row
    #pragma unroll
    for (int r = 0; r < 2; r++){
      int g2 = l + 64*r;
      int el = g2 >> 3, d0 = (g2 & 7) << 3;
      int er = e0 + w*32 + et*16 + el;
      if (er < NEDGE){
        float4 q0 = *(const float4*)&tb[el*68 + d0];
        float4 q1 = *(const float4*)&tb[el*68 + d0 + 4];
        f16x8 h = {(f16)q0.x,(f16)q0.y,(f16)q0.z,(f16)q0.w,
                   (f16)q1.x,(f16)q1.y,(f16)q1.z,(f16)q1.w};
        *(f16x8*)(rel + (size_t)er*64 + d0) = h;
      }
    }
  }
}

// ---------------------------------------------------------------------------
// User side: one 16-lane group per user (4 users/wave, 16 users/block).
// ---------------------------------------------------------------------------
__global__ __launch_bounds__(256) void k_user(
    const float* __restrict__ ent, const float* __restrict__ usr,
    const float* __restrict__ w3,
    const int2* __restrict__ pair_u, const int* __restrict__ rtype,
    const f16* __restrict__ rel,
    const int* __restrict__ off_u, float* __restrict__ out_user)
{
  const int t = threadIdx.x;
  const int c = t & 15;
  const int u = blockIdx.x*16 + (t >> 4);
  if (u >= NUSR) return;
  const int beg = off_u[u], end = off_u[u+1];

  const f32x4 z = {0.f,0.f,0.f,0.f};
  f32x4 s0 = z, s1 = z, s2 = z;
  int c0 = 0, c1 = 0, c2 = 0;
  for (int k = beg; k < end; k++){
    int item = pair_u[k].y;
    int f = rtype[k];
    f32x4 ip = *(const f32x4*)(ent + (size_t)item*64 + (c<<2));
    if (f == 0){ s0 += ip; c0++; }
    else if (f == 1){ s1 += ip; c1++; }
    else { s2 += ip; c2++; }
  }
  const float d0 = fmaxf((float)c0, 1.f);
  const float d1 = fmaxf((float)c1, 1.f);
  const float d2 = fmaxf((float)c2, 1.f);

  f32x4 a0 = z, a1 = z, a2 = z;
  for (int k = beg; k < end; k++){
    int item = pair_u[k].y;
    int f = rtype[k];
    f32x4 ip = *(const f32x4*)(ent + (size_t)item*64 + (c<<2));
    f16x4 hv = *(const f16x4*)(rel + (size_t)k*64 + (c<<2));
    f32x4 rv = {(float)hv[0], (float)hv[1], (float)hv[2], (float)hv[3]};
    f32x4 sf = (f == 0) ? s0 : ((f == 1) ? s1 : s2);
    float dd = (f == 0) ? d0 : ((f == 1) ? d1 : d2);
    float p = rv[0]*sf[0] + rv[1]*sf[1] + rv[2]*sf[2] + rv[3]*sf[3];
    #pragma unroll
    for (int m = 1; m < 16; m <<= 1) p += __shfl_xor(p, m);
    float sim = p / dd;                 // dot(rel, u_) with mean folded in
    f32x4 tv = ip * sim;
    if (f == 0) a0 += tv; else if (f == 1) a1 += tv; else a2 += tv;
  }

  float wa = w3[0], wb = w3[1], wc = w3[2];
  float mx = fmaxf(wa, fmaxf(wb, wc));
  float ea = expf(wa-mx), eb = expf(wb-mx), ec = expf(wc-mx);
  float inv = 1.f/(ea+eb+ec);
  f32x4 ue = *(const f32x4*)(usr + (size_t)u*64 + (c<<2));
  f32x4 av[3] = {a0, a1, a2};
  float dv[3] = {d0, d1, d2}, wv[3] = {ea*inv, eb*inv, ec*inv};
  f32x4 o = z;
  #pragma unroll
  for (int f = 0; f < 3; f++){
    f32x4 v = av[f] / dv[f];
    float n2 = v[0]*v[0] + v[1]*v[1] + v[2]*v[2] + v[3]*v[3];
    #pragma unroll
    for (int m = 1; m < 16; m <<= 1) n2 += __shfl_xor(n2, m);
    float n = sqrtf(n2);
    float fac = (n2/(n2 + 1.f)) / fmaxf(n, 1e-12f);
    o += (v * fac + ue) * wv[f];
  }
  *(f32x4*)(out_user + (size_t)u*64 + (c<<2)) = o;
}

// ---------------------------------------------------------------------------
// Entity side: one 16-lane group per entity (4/wave, 16/block).
// ---------------------------------------------------------------------------
__global__ __launch_bounds__(256) void k_ent(
    const float* __restrict__ ent, const float* __restrict__ usr,
    const int2* __restrict__ pair_i, const f16* __restrict__ rel,
    const int* __restrict__ off_i, float* __restrict__ out_ent)
{
  const int t = threadIdx.x;
  const int c = t & 15;
  const int i = blockIdx.x*16 + (t >> 4);
  if (i >= NENT) return;
  const int beg = off_i[i], end = off_i[i+1];

  const f32x4 z = {0.f,0.f,0.f,0.f};
  f32x4 s = z;
  for (int k = beg; k < end; k++){
    int us = pair_i[k].x;
    s += *(const f32x4*)(usr + (size_t)us*64 + (c<<2));
  }
  const float d = fmaxf((float)(end - beg), 1.f);

  f32x4 a = z;
  for (int k = beg; k < end; k++){
    int us = pair_i[k].x;
    f32x4 up = *(const f32x4*)(usr + (size_t)us*64 + (c<<2));
    f16x4 hv = *(const f16x4*)(rel + (size_t)k*64 + (c<<2));
    f32x4 rv = {(float)hv[0], (float)hv[1], (float)hv[2], (float)hv[3]};
    float p = rv[0]*s[0] + rv[1]*s[1] + rv[2]*s[2] + rv[3]*s[3];
    #pragma unroll
    for (int m = 1; m < 16; m <<= 1) p += __shfl_xor(p, m);
    a += up * (p / d);
  }

  f32x4 v = a / d;
  float n2 = v[0]*v[0] + v[1]*v[1] + v[2]*v[2] + v[3]*v[3];
  #pragma unroll
  for (int m = 1; m < 16; m <<= 1) n2 += __shfl_xor(n2, m);
  float n = sqrtf(n2);
  float fac = (n2/(n2 + 1.f)) / fmaxf(n, 1e-12f);
  f32x4 ev = *(const f32x4*)(ent + (size_t)i*64 + (c<<2));
  *(f32x4*)(out_ent + (size_t)i*64 + (c<<2)) = v * fac + ev;
}

// ---------------------------------------------------------------------------
// Workspace layout (f32 element offsets). rel is fp16 (64 MB used).
//   rel     f16 [E*64]   @ 0            (64 MB used)
//   zero-block           @ 32,000,000:  deg_u(100k) cur_u(100k) deg_i(200k) cur_i(200k)
//   off_u   [U+1]        @ 32,600,000
//   off_i   [ENT+1]      @ 32,700,004
//   pair_u  int2 [E]     @ 32,900,008   (byte offset %8 == 0)
//   pair_i  int2 [E]     @ 33,900,008
//   rtype   [E]          @ 34,900,008
//   part    [NBT]        @ 35,400,008
// ---------------------------------------------------------------------------
extern "C" void kernel_launch(void* const* d_in, const int* in_sizes, int n_in,
                              void* d_out, int out_size, void* d_ws, size_t ws_size,
                              hipStream_t stream) {
  const float* ent = (const float*)d_in[0];
  const float* usr = (const float*)d_in[1];
  const float* lat = (const float*)d_in[2];
  const int*   ui  = (const int*)d_in[3];
  const int*   ii  = (const int*)d_in[4];
  const float* Ww  = (const float*)d_in[5];
  const float* Wb  = (const float*)d_in[6];
  const float* Wiw = (const float*)d_in[7];
  const float* Wib = (const float*)d_in[8];
  const float* w3  = (const float*)d_in[9];

  float* ws = (float*)d_ws;
  f16*   rel    = (f16*)ws;
  int*   deg_u  = (int*)(ws + 32000000ull);
  int*   cur_u  = deg_u + 100000;
  int*   deg_i  = cur_u + 100000;
  int*   cur_i  = deg_i + 200000;
  int*   off_u  = (int*)(ws + 32600000ull);
  int*   off_i  = (int*)(ws + 32700004ull);
  int2*  pair_u = (int2*)(ws + 32900008ull);
  int2*  pair_i = (int2*)(ws + 33900008ull);
  int*   rtype  = (int*)(ws + 34900008ull);
  int*   part   = (int*)(ws + 35400008ull);

  float* out_ent  = (float*)d_out;
  float* out_user = (float*)d_out + (size_t)NENT*64;

  hipMemsetAsync(deg_u, 0, 600000*sizeof(int), stream);   // deg+cur, both sides

  k_hist<<<1954, 256, 0, stream>>>(ui, ii, deg_u, deg_i);
  k_scan_part<<<NBT, 1024, 0, stream>>>(deg_u, off_u, deg_i, off_i, part);
  k_scan_add<<<NBT, 1024, 0, stream>>>(off_u, off_i, part);
  k_scatter<<<1954, 256, 0, stream>>>(ui, ii, off_u, off_i,
                                      cur_u, cur_i, pair_u, pair_i);

  // relation_ui = leaky(concat([user, item]) @ Ww^T + b), + argmax -> rtype
  k_matvec<1,0><<<1954, 512, 0, stream>>>(usr, ent, pair_u, lat, Ww, Wb,
                                          rel, rtype);
  k_user<<<6250, 256, 0, stream>>>(ent, usr, w3, pair_u, rtype, rel,
                                   off_u, out_user);
  // relation_iu = leaky(concat([item, user]) @ Wiw^T + b)  (reuses rel buffer)
  k_matvec<0,1><<<1954, 512, 0, stream>>>(ent, usr, pair_i, lat, Wiw, Wib,
                                          rel, rtype);
  k_ent<<<12500, 256, 0, stream>>>(ent, usr, pair_i, rel,
                                   off_i, out_ent);
}